// Round 7
// baseline (1670.427 us; speedup 1.0000x reference)
//
#include <hip/hip_runtime.h>
#include <math.h>

// ---------------------------------------------------------------------------
// GlobalSceneEncoder: 4-stage point-transformer encoder.
// FPS/KNN: bit-exact f32 replication of the numpy reference (no FMA,
// fixed summation order), u32/u64 monotone-key reductions.
// FPS v5: DPP wave-max reduce + register position carry (R5 skeleton).
// GEMMs: f16 MFMA w/ fp32 accum. Everything else fp32.
// B=4, N0=4096, D=384, K=16.
// ---------------------------------------------------------------------------

using half8 = __attribute__((ext_vector_type(8))) _Float16;
using f32x4 = __attribute__((ext_vector_type(4))) float;

__device__ __forceinline__ float d2f(float ax, float ay, float az,
                                     float bx, float by, float bz)
{
  // exact np order: ((dx*dx + dy*dy) + dz*dz), no contraction
  const float dx = __fsub_rn(ax, bx);
  const float dy = __fsub_rn(ay, by);
  const float dz = __fsub_rn(az, bz);
  return __fadd_rn(__fadd_rn(__fmul_rn(dx, dx), __fmul_rn(dy, dy)),
                   __fmul_rn(dz, dz));
}

// ---- DPP u32 max reduce across wave64, result broadcast via readlane ------
template<int CTRL>
__device__ __forceinline__ unsigned dppmax_step(unsigned v)
{
  const unsigned o = (unsigned)__builtin_amdgcn_update_dpp(
      (int)v, (int)v, CTRL, 0xF, 0xF, false);
  return o > v ? o : v;
}
__device__ __forceinline__ unsigned wave_max_bcast(unsigned v)
{
  v = dppmax_step<0x111>(v);   // row_shr:1
  v = dppmax_step<0x112>(v);   // row_shr:2
  v = dppmax_step<0x114>(v);   // row_shr:4
  v = dppmax_step<0x118>(v);   // row_shr:8
  v = dppmax_step<0x142>(v);   // row_bcast:15
  v = dppmax_step<0x143>(v);   // row_bcast:31
  return (unsigned)__builtin_amdgcn_readlane((int)v, 63);
}

// ---------------- split pts -> pos0, x0 ----------------
__global__ __launch_bounds__(128) void split_kernel(
    const float* __restrict__ pts, float* __restrict__ pos0, float* __restrict__ x0)
{
  const int n = blockIdx.x;
  const int b = blockIdx.y;
  const float* src = pts + ((long)b * 4096 + n) * 387;
  float* pd = pos0 + ((long)b * 4096 + n) * 3;
  float* xd = x0 + ((long)b * 4096 + n) * 384;
  for (int e = threadIdx.x; e < 387; e += 128) {
    float v = src[e];
    if (e < 3) pd[e] = v; else xd[e - 3] = v;
  }
}

// ---------------- weight transpose + f16 convert: Wt[n][k] = W[k][n] -------
struct TP { const float* src[5]; _Float16* dst; };
__global__ __launch_bounds__(256) void transpose_kernel(TP p)
{
  const int z = blockIdx.z;
  const float* S = p.src[z >> 2] + (long)(z & 3) * 147456;
  _Float16* Dst = p.dst + (long)z * 147456;
  const int k0 = blockIdx.x * 32, n0 = blockIdx.y * 32;
  __shared__ float tile[32][33];
  const int ti = threadIdx.x & 31, tj = threadIdx.x >> 5;
  #pragma unroll
  for (int p8 = 0; p8 < 32; p8 += 8)
    tile[tj + p8][ti] = S[(long)(k0 + tj + p8) * 384 + n0 + ti];
  __syncthreads();
  #pragma unroll
  for (int p8 = 0; p8 < 32; p8 += 8)
    Dst[(long)(n0 + tj + p8) * 384 + k0 + ti] = (_Float16)tile[ti][tj + p8];
}

// ---------------- FPS v5: DPP reduce, register pos-carry, tiny LDS ---------
// Contiguous ownership: thread t owns points [t*NPT, (t+1)*NPT) so
// lowest-lane tie-break == lowest-index tie-break.
template<int NPTS, int NTHR>
__global__ __launch_bounds__(NTHR, 1) void fps_kernel(
    const float* __restrict__ pos,
    int* __restrict__ idx_out, float* __restrict__ pos_out)
{
  constexpr int NPT = NPTS / NTHR;
  constexpr int NW = NTHR / 64;
  constexpr int M = NPTS / 4;
  const int b = blockIdx.x;
  pos += (long)b * NPTS * 3; idx_out += (long)b * M; pos_out += (long)b * M * 3;
  const int t = threadIdx.x;

  __shared__ unsigned long long s_key[2][NW > 1 ? NW : 1];
  __shared__ float4 s_qp[2][NW > 1 ? NW : 1];

  float px[NPT], py[NPT], pz[NPT], dmin[NPT];
  #pragma unroll
  for (int i = 0; i < NPT; i++) {
    const int j = t * NPT + i;
    px[i] = pos[j*3]; py[i] = pos[j*3+1]; pz[i] = pos[j*3+2];
  }
  const float sx = pos[0], sy = pos[1], sz = pos[2];
  #pragma unroll
  for (int i = 0; i < NPT; i++)
    dmin[i] = d2f(px[i], py[i], pz[i], sx, sy, sz);
  if (t == 0) { idx_out[0] = 0; pos_out[0] = sx; pos_out[1] = sy; pos_out[2] = sz; }

  for (int m = 1; m < M; ++m) {
    // ---- local tournament carrying (val, idx, x, y, z); strict > keeps
    //      the lowest local index on ties ----
    float bv = dmin[0]; int bj = t * NPT;
    float cx = px[0], cy = py[0], cz = pz[0];
    #pragma unroll
    for (int i = 1; i < NPT; i++) {
      const bool g = dmin[i] > bv;
      bv = g ? dmin[i] : bv;
      bj = g ? (t * NPT + i) : bj;
      cx = g ? px[i] : cx; cy = g ? py[i] : cy; cz = g ? pz[i] : cz;
    }
    // ---- DPP wave max (uniform result) + winner lane via ballot ----
    const unsigned myub = __float_as_uint(bv);
    const unsigned wmax = wave_max_bcast(myub);
    const unsigned long long mk = __ballot(myub == wmax);
    const int srclane = __builtin_ctzll(mk);
    const int wj = __shfl(bj, srclane);
    const float wx = __shfl(cx, srclane);
    const float wy = __shfl(cy, srclane);
    const float wz = __shfl(cz, srclane);

    int sel; float qx, qy, qz;
    if (NW > 1) {
      const int p = m & 1;
      if ((t & 63) == 0) {
        s_key[p][t >> 6] =
            ((unsigned long long)wmax << 32) | (unsigned)(NPTS - 1 - wj);
        s_qp[p][t >> 6] = make_float4(wx, wy, wz, 0.f);
      }
      __syncthreads();
      unsigned long long kb = s_key[p][0]; int widx = 0;
      #pragma unroll
      for (int w2 = 1; w2 < NW; w2++) {
        const unsigned long long o = s_key[p][w2];
        if (o > kb) { kb = o; widx = w2; }
      }
      sel = NPTS - 1 - (int)(kb & 0xFFFFFFFFu);
      const float4 qp = s_qp[p][widx];
      qx = qp.x; qy = qp.y; qz = qp.z;
    } else {
      sel = wj; qx = wx; qy = wy; qz = wz;
    }
    // ---- exact-f32 update ----
    #pragma unroll
    for (int i = 0; i < NPT; i++) {
      const float dd = d2f(px[i], py[i], pz[i], qx, qy, qz);
      dmin[i] = fminf(dmin[i], dd);
    }
    if (t == 0) { idx_out[m] = sel; pos_out[m*3] = qx; pos_out[m*3+1] = qy; pos_out[m*3+2] = qz; }
  }
}

// ---------------- KNN: one wave/query, 16 passes, u64 (dist,j) keys --------
template<int C>
__global__ __launch_bounds__(64) void knn_kernel(
    const float* __restrict__ pos, const float* __restrict__ qpos,
    int N, int M, int* __restrict__ nbr, float* __restrict__ vld, float r2)
{
  const int m = blockIdx.x, b = blockIdx.y;
  pos += (long)b * N * 3; qpos += (long)b * M * 3;
  nbr += (long)b * (1024 * 16); vld += (long)b * (1024 * 16);
  const int lane = threadIdx.x;
  const float qx = qpos[m*3], qy = qpos[m*3+1], qz = qpos[m*3+2];
  unsigned long long key[C];
  #pragma unroll
  for (int c = 0; c < C; c++) {
    const int j = c * 64 + lane;
    const float dd = d2f(pos[j*3], pos[j*3+1], pos[j*3+2], qx, qy, qz);
    key[c] = ((unsigned long long)__float_as_uint(dd) << 32) | (unsigned)j;
  }
  unsigned long long prev = 0;
  for (int k = 0; k < 16; k++) {
    unsigned long long best = ~0ull;
    #pragma unroll
    for (int c = 0; c < C; c++) {
      const bool take = (k == 0) || (key[c] > prev);
      if (take && key[c] < best) best = key[c];
    }
    #pragma unroll
    for (int off = 32; off; off >>= 1) {
      const unsigned long long o = __shfl_xor(best, off);
      if (o < best) best = o;
    }
    prev = best;
    if (lane == 0) {
      nbr[m*16+k] = (int)(best & 0xFFFFFFFFu);
      const float dd = __uint_as_float((unsigned)(best >> 32));
      vld[m*16+k] = (dd <= r2) ? 1.0f : 0.0f;
    }
  }
}

// ---------------- f16 MFMA GEMM, 64x64 tile, BK=32, 3 A-operand modes ------
struct GemmP {
  const float* A; long sA;
  const _Float16* Wt;          // pre-transposed f16 weights: Wt[n][k]
  const float* bias;
  float* C; long sC;
  int R;
  const int* gather; long sG;
  const float* qpos; long sQ;
  const float* pos;  long sP;
  const int* nbr;    long sN;
  const float* pw1;
  const float* pb1;
  const float* adst; long sAD;
  const float* asrc; long sAS;
  int row0;
};

template<int AMODE, bool GATHER, bool BIAS, bool RELU>
__global__ __launch_bounds__(256) void mgemm_kernel(GemmP p)
{
  const int b = blockIdx.z;
  const int rb = blockIdx.x * 64;
  const int cb = blockIdx.y * 64;
  const int t = threadIdx.x;
  const float* A = p.A ? (p.A + (long)b * p.sA) : nullptr;
  float* C = p.C + (long)b * p.sC;
  const int* gat = GATHER ? (p.gather + (long)b * p.sG) : nullptr;
  const int* nbrb = (AMODE != 0) ? (p.nbr + (long)b * p.sN) : nullptr;

  __shared__ _Float16 As[64][40];
  __shared__ _Float16 Bs[64][40];

  const int w = t >> 6, lane = t & 63;
  const int wm = w & 1, wn = w >> 1;
  const int quad = lane >> 4, l16 = lane & 15;

  f32x4 acc[2][2] = {};

  const int sr = t >> 2;
  const int sk = (t & 3) << 3;
  const int ar = rb + sr;

  const float* arow = nullptr;
  const float* adrow = nullptr;
  const float* asrow = nullptr;
  bool avalid = true;
  float rx = 0.f, ry = 0.f, rz = 0.f;
  if (AMODE == 0) {
    avalid = (ar < p.R);
    long srcrow = 0;
    if (avalid) srcrow = GATHER ? (long)gat[ar] : (long)ar;
    arow = A + srcrow * 384;
  } else {
    const int grow = p.row0 + ar;
    const int mq = grow >> 4;
    const int n = nbrb[grow];
    if (AMODE == 1) {
      const float* qposb = p.qpos + (long)b * p.sQ;
      const float* posb = p.pos + (long)b * p.sP;
      rx = qposb[mq*3+0] - posb[n*3+0];
      ry = qposb[mq*3+1] - posb[n*3+1];
      rz = qposb[mq*3+2] - posb[n*3+2];
    } else {
      arow = A + (long)ar * 384;
      adrow = p.adst + (long)b * p.sAD + (long)mq * 384;
      asrow = p.asrc + (long)b * p.sAS + (long)n * 384;
    }
  }

  for (int k0 = 0; k0 < 384; k0 += 32) {
    float a8[8];
    if (AMODE == 0) {
      if (avalid) {
        const float4 u = *(const float4*)(arow + k0 + sk);
        const float4 v = *(const float4*)(arow + k0 + sk + 4);
        a8[0]=u.x; a8[1]=u.y; a8[2]=u.z; a8[3]=u.w;
        a8[4]=v.x; a8[5]=v.y; a8[6]=v.z; a8[7]=v.w;
      } else {
        #pragma unroll
        for (int j = 0; j < 8; j++) a8[j] = 0.f;
      }
    } else if (AMODE == 1) {
      const int kc = k0 + sk;
      const float4 w0a = *(const float4*)(p.pw1 + kc);
      const float4 w0b = *(const float4*)(p.pw1 + kc + 4);
      const float4 w1a = *(const float4*)(p.pw1 + 384 + kc);
      const float4 w1b = *(const float4*)(p.pw1 + 384 + kc + 4);
      const float4 w2a = *(const float4*)(p.pw1 + 768 + kc);
      const float4 w2b = *(const float4*)(p.pw1 + 768 + kc + 4);
      const float4 b1a = *(const float4*)(p.pb1 + kc);
      const float4 b1b = *(const float4*)(p.pb1 + kc + 4);
      a8[0] = fmaxf(rx*w0a.x + ry*w1a.x + rz*w2a.x + b1a.x, 0.f);
      a8[1] = fmaxf(rx*w0a.y + ry*w1a.y + rz*w2a.y + b1a.y, 0.f);
      a8[2] = fmaxf(rx*w0a.z + ry*w1a.z + rz*w2a.z + b1a.z, 0.f);
      a8[3] = fmaxf(rx*w0a.w + ry*w1a.w + rz*w2a.w + b1a.w, 0.f);
      a8[4] = fmaxf(rx*w0b.x + ry*w1b.x + rz*w2b.x + b1b.x, 0.f);
      a8[5] = fmaxf(rx*w0b.y + ry*w1b.y + rz*w2b.y + b1b.y, 0.f);
      a8[6] = fmaxf(rx*w0b.z + ry*w1b.z + rz*w2b.z + b1b.z, 0.f);
      a8[7] = fmaxf(rx*w0b.w + ry*w1b.w + rz*w2b.w + b1b.w, 0.f);
    } else {
      const int kc = k0 + sk;
      const float4 d0 = *(const float4*)(arow + kc);
      const float4 d1 = *(const float4*)(arow + kc + 4);
      const float4 a0 = *(const float4*)(adrow + kc);
      const float4 a1 = *(const float4*)(adrow + kc + 4);
      const float4 s0 = *(const float4*)(asrow + kc);
      const float4 s1 = *(const float4*)(asrow + kc + 4);
      a8[0] = a0.x - s0.x + d0.x; a8[1] = a0.y - s0.y + d0.y;
      a8[2] = a0.z - s0.z + d0.z; a8[3] = a0.w - s0.w + d0.w;
      a8[4] = a1.x - s1.x + d1.x; a8[5] = a1.y - s1.y + d1.y;
      a8[6] = a1.z - s1.z + d1.z; a8[7] = a1.w - s1.w + d1.w;
    }
    const half8 bv = *(const half8*)(p.Wt + (long)(cb + sr) * 384 + k0 + sk);

    __syncthreads();
    half8 av;
    #pragma unroll
    for (int j = 0; j < 8; j++) av[j] = (_Float16)a8[j];
    *(half8*)&As[sr][sk] = av;
    *(half8*)&Bs[sr][sk] = bv;
    __syncthreads();

    const half8 fa0 = *(const half8*)&As[wm*32 + l16][quad*8];
    const half8 fa1 = *(const half8*)&As[wm*32 + 16 + l16][quad*8];
    const half8 fb0 = *(const half8*)&Bs[wn*32 + l16][quad*8];
    const half8 fb1 = *(const half8*)&Bs[wn*32 + 16 + l16][quad*8];
    acc[0][0] = __builtin_amdgcn_mfma_f32_16x16x32_f16(fa0, fb0, acc[0][0], 0, 0, 0);
    acc[0][1] = __builtin_amdgcn_mfma_f32_16x16x32_f16(fa0, fb1, acc[0][1], 0, 0, 0);
    acc[1][0] = __builtin_amdgcn_mfma_f32_16x16x32_f16(fa1, fb0, acc[1][0], 0, 0, 0);
    acc[1][1] = __builtin_amdgcn_mfma_f32_16x16x32_f16(fa1, fb1, acc[1][1], 0, 0, 0);
  }

  float bi0 = 0.f, bi1 = 0.f;
  if (BIAS) {
    bi0 = p.bias[cb + wn*32 + l16];
    bi1 = p.bias[cb + wn*32 + 16 + l16];
  }
  #pragma unroll
  for (int i = 0; i < 2; i++) {
    const int base = rb + wm*32 + i*16;
    if (base < p.R) {
      const int r0 = base + quad*4;
      #pragma unroll
      for (int j = 0; j < 2; j++) {
        const int col = cb + wn*32 + j*16 + l16;
        const float bb = j ? bi1 : bi0;
        #pragma unroll
        for (int reg = 0; reg < 4; reg++) {
          float v = acc[i][j][reg] + bb;
          if (RELU) v = fmaxf(v, 0.f);
          C[(long)(r0 + reg) * 384 + col] = v;
        }
      }
    }
  }
}

// ---------------- masked softmax over K + weighted sum + LayerNorm ---------
__global__ __launch_bounds__(128) void attnln_kernel(
    const float* __restrict__ alpha, const float* __restrict__ delta,
    const float* __restrict__ vbuf, const int* __restrict__ nbr,
    const float* __restrict__ vldb, const float* __restrict__ lng,
    const float* __restrict__ lnb, float* __restrict__ xout,
    int q0, long sCh, long sV, long sNb, long sX)
{
  const int ml = blockIdx.x, b = blockIdx.y;
  const int m = q0 + ml;
  alpha += (long)b * sCh; delta += (long)b * sCh; vbuf += (long)b * sV;
  nbr += (long)b * sNb; vldb += (long)b * sNb; xout += (long)b * sX;
  const int t = threadIdx.x;

  int nb[16]; float vl[16];
  #pragma unroll
  for (int k = 0; k < 16; k++) { nb[k] = nbr[m*16+k]; vl[k] = vldb[m*16+k]; }

  const long rbase = (long)ml * 16 * 384;
  float av[16][3];
  #pragma unroll
  for (int k = 0; k < 16; k++)
    #pragma unroll
    for (int i = 0; i < 3; i++) {
      const float a = alpha[rbase + k*384 + t + i*128];
      av[k][i] = (vl[k] > 0.5f) ? a : -1e30f;
    }
  float mx[3] = {-3.4e38f, -3.4e38f, -3.4e38f};
  #pragma unroll
  for (int k = 0; k < 16; k++)
    #pragma unroll
    for (int i = 0; i < 3; i++) mx[i] = fmaxf(mx[i], av[k][i]);
  float sm[3] = {0.f, 0.f, 0.f};
  #pragma unroll
  for (int k = 0; k < 16; k++)
    #pragma unroll
    for (int i = 0; i < 3; i++) { const float e = expf(av[k][i] - mx[i]); av[k][i] = e; sm[i] += e; }
  float rs[3];
  #pragma unroll
  for (int i = 0; i < 3; i++) rs[i] = 1.0f / sm[i];
  float o[3] = {0.f, 0.f, 0.f};
  #pragma unroll
  for (int k = 0; k < 16; k++) {
    const long nrow = (long)nb[k] * 384;
    #pragma unroll
    for (int i = 0; i < 3; i++) {
      const int dd = t + i * 128;
      const float vv = vbuf[nrow + dd] + delta[rbase + k*384 + dd];
      o[i] += (av[k][i] * rs[i] * vl[k]) * vv;
    }
  }
  __shared__ float sred[2];
  float s1 = o[0] + o[1] + o[2];
  #pragma unroll
  for (int off = 32; off; off >>= 1) s1 += __shfl_xor(s1, off);
  if ((t & 63) == 0) sred[t >> 6] = s1;
  __syncthreads();
  const float mean = (sred[0] + sred[1]) * (1.0f / 384.0f);
  __syncthreads();
  float s2 = 0.f;
  #pragma unroll
  for (int i = 0; i < 3; i++) { const float dd = o[i] - mean; s2 += dd * dd; }
  #pragma unroll
  for (int off = 32; off; off >>= 1) s2 += __shfl_xor(s2, off);
  if ((t & 63) == 0) sred[t >> 6] = s2;
  __syncthreads();
  const float var = (sred[0] + sred[1]) * (1.0f / 384.0f);
  const float rstd = 1.0f / sqrtf(var + 1e-5f);
  #pragma unroll
  for (int i = 0; i < 3; i++) {
    const int dd = t + i * 128;
    xout[(long)m * 384 + dd] = (o[i] - mean) * rstd * lng[dd] + lnb[dd];
  }
}

// ---------------- final projection + LayerNorm -----------------------------
__global__ __launch_bounds__(384) void feat_kernel(
    const float* __restrict__ x4, const float* __restrict__ pw,
    const float* __restrict__ pb, const float* __restrict__ g,
    const float* __restrict__ be, float* __restrict__ outf)
{
  const int row = blockIdx.x, b = blockIdx.y;
  const long r = (long)b * 16 + row;
  const int d = threadIdx.x;
  __shared__ float xs[384];
  xs[d] = x4[r * 384 + d];
  __syncthreads();
  float acc = pb[d];
  #pragma unroll 8
  for (int j = 0; j < 384; j++) acc = fmaf(xs[j], pw[(long)j * 384 + d], acc);
  __shared__ float sred[6];
  float s = acc;
  #pragma unroll
  for (int off = 32; off; off >>= 1) s += __shfl_xor(s, off);
  if ((d & 63) == 0) sred[d >> 6] = s;
  __syncthreads();
  const float mean = (sred[0]+sred[1]+sred[2]+sred[3]+sred[4]+sred[5]) * (1.0f/384.0f);
  __syncthreads();
  float dv = (acc - mean) * (acc - mean);
  #pragma unroll
  for (int off = 32; off; off >>= 1) dv += __shfl_xor(dv, off);
  if ((d & 63) == 0) sred[d >> 6] = dv;
  __syncthreads();
  const float var = (sred[0]+sred[1]+sred[2]+sred[3]+sred[4]+sred[5]) * (1.0f/384.0f);
  const float rstd = 1.0f / sqrtf(var + 1e-5f);
  outf[r * 384 + d] = (acc - mean) * rstd * g[d] + be[d];
}

// ---------------- pos + pad outputs ----------------------------------------
__global__ void tail_kernel(const float* __restrict__ p4, float* __restrict__ out)
{
  const int t = threadIdx.x;
  if (t < 192) out[t] = p4[t];
  if (t < 64) out[192 + 24576 + t] = 0.0f;
}

// ---------------------------------------------------------------------------
extern "C" void kernel_launch(void* const* d_in, const int* in_sizes, int n_in,
                              void* d_out, int out_size, void* d_ws, size_t ws_size,
                              hipStream_t stream)
{
  (void)in_sizes; (void)n_in; (void)out_size; (void)ws_size;
  const float* pts    = (const float*)d_in[0];
  const float* lin_w  = (const float*)d_in[1];
  const float* lin_b  = (const float*)d_in[2];
  const float* src_w  = (const float*)d_in[3];
  const float* dst_w  = (const float*)d_in[4];
  const float* pos_w1 = (const float*)d_in[5];
  const float* pos_b1 = (const float*)d_in[6];
  const float* pos_w2 = (const float*)d_in[7];
  const float* pos_b2 = (const float*)d_in[8];
  const float* attn_w = (const float*)d_in[9];
  const float* attn_b = (const float*)d_in[10];
  const float* ln_g   = (const float*)d_in[11];
  const float* ln_b   = (const float*)d_in[12];
  const float* proj_w = (const float*)d_in[13];
  const float* proj_b = (const float*)d_in[14];
  const float* pln_g  = (const float*)d_in[15];
  const float* pln_b  = (const float*)d_in[16];
  float* out = (float*)d_out;

  // ---- workspace layout (R5-proven, chunked) ----
  constexpr long SX0 = 4096L*384, SX1 = 1024L*384, SX2 = 256L*384, SX3 = 64L*384, SX4 = 16L*384;
  constexpr long SP0 = 4096L*3, SP1 = 1024L*3, SP2 = 256L*3, SP3 = 64L*3, SP4 = 16L*3;
  constexpr long SV  = 4096L*384;
  constexpr long SAD = 1024L*384;
  constexpr long SCH = 4096L*384;
  constexpr long SNB = 1024L*16;

  _Float16* wt = (_Float16*)d_ws;
  float* ws = (float*)(wt + 20L * 147456);
  float* x0 = ws; ws += 4*SX0;
  float* x1 = ws; ws += 4*SX1;
  float* x2 = ws; ws += 4*SX2;
  float* x3 = ws; ws += 4*SX3;
  float* x4 = ws; ws += 4*SX4;
  float* p0 = ws; ws += 4*SP0;
  float* p1 = ws; ws += 4*SP1;
  float* p2 = ws; ws += 4*SP2;
  float* p3 = ws; ws += 4*SP3;
  float* p4 = ws; ws += 4*SP4;
  float* vb = ws; ws += 4*SV;
  float* asb = ws; ws += 4*SV;
  float* adb = ws; ws += 4*SAD;
  float* db = ws; ws += 4*SCH;
  float* ab = ws; ws += 4*SCH;
  float* vld = ws; ws += 4*SNB;
  int* nb = (int*)ws; ws += 4*SNB;
  int* ix[4];
  ix[0] = (int*)ws; ws += 4*1024;
  ix[1] = (int*)ws; ws += 4*256;
  ix[2] = (int*)ws; ws += 4*64;
  ix[3] = (int*)ws; ws += 4*16;

  const int Ns[4] = {4096, 1024, 256, 64};
  const int Ms[4] = {1024, 256, 64, 16};
  const float R2[4] = {1.0f, 4.0f, 16.0f, 64.0f};
  float* X[5] = {x0, x1, x2, x3, x4};
  float* P[5] = {p0, p1, p2, p3, p4};
  long SPs[5] = {SP0, SP1, SP2, SP3, SP4};
  long SXs[5] = {SX0, SX1, SX2, SX3, SX4};

  split_kernel<<<dim3(4096, 4), 128, 0, stream>>>(pts, p0, x0);

  {
    TP tp{};
    tp.src[0] = lin_w; tp.src[1] = src_w; tp.src[2] = dst_w;
    tp.src[3] = pos_w2; tp.src[4] = attn_w;
    tp.dst = wt;
    transpose_kernel<<<dim3(12, 12, 20), 256, 0, stream>>>(tp);
  }

  // FPS chain (v5)
  fps_kernel<4096, 256><<<dim3(4), 256, 0, stream>>>(P[0], ix[0], P[1]);
  fps_kernel<1024, 256><<<dim3(4), 256, 0, stream>>>(P[1], ix[1], P[2]);
  fps_kernel<256, 64><<<dim3(4), 64, 0, stream>>>(P[2], ix[2], P[3]);
  fps_kernel<64, 64><<<dim3(4), 64, 0, stream>>>(P[3], ix[3], P[4]);

  for (int s = 0; s < 4; s++) {
    const int N = Ns[s], M = Ms[s];
    switch (s) {
      case 0: knn_kernel<64><<<dim3(M, 4), 64, 0, stream>>>(P[s], P[s+1], N, M, nb, vld, R2[s]); break;
      case 1: knn_kernel<16><<<dim3(M, 4), 64, 0, stream>>>(P[s], P[s+1], N, M, nb, vld, R2[s]); break;
      case 2: knn_kernel<4><<<dim3(M, 4), 64, 0, stream>>>(P[s], P[s+1], N, M, nb, vld, R2[s]); break;
      default: knn_kernel<1><<<dim3(M, 4), 64, 0, stream>>>(P[s], P[s+1], N, M, nb, vld, R2[s]); break;
    }
    // v = x@lw + lb
    {
      GemmP g{}; g.A = X[s]; g.sA = SXs[s]; g.Wt = wt + (long)(0*4+s)*147456; g.bias = lin_b + (long)s*384;
      g.C = vb; g.sC = SV; g.R = N;
      mgemm_kernel<0, false, true, false><<<dim3(N/64, 6, 4), 256, 0, stream>>>(g);
    }
    // a_src = x@sw
    {
      GemmP g{}; g.A = X[s]; g.sA = SXs[s]; g.Wt = wt + (long)(1*4+s)*147456;
      g.C = asb; g.sC = SV; g.R = N;
      mgemm_kernel<0, false, false, false><<<dim3(N/64, 6, 4), 256, 0, stream>>>(g);
    }
    // a_dst = x[idx]@dw
    {
      GemmP g{}; g.A = X[s]; g.sA = SXs[s]; g.Wt = wt + (long)(2*4+s)*147456;
      g.C = adb; g.sC = SAD; g.R = M; g.gather = ix[s]; g.sG = M;
      mgemm_kernel<0, true, false, false><<<dim3((M+63)/64, 6, 4), 256, 0, stream>>>(g);
    }
    const int nch = (M + 255) / 256;
    for (int c = 0; c < nch; c++) {
      const int q0 = c * 256;
      const int Mc = (M - q0 < 256) ? (M - q0) : 256;
      const int rows = Mc * 16;
      {
        GemmP g{}; g.Wt = wt + (long)(3*4+s)*147456; g.bias = pos_b2 + (long)s*384;
        g.C = db; g.sC = SCH; g.R = rows;
        g.qpos = P[s+1]; g.sQ = SPs[s+1]; g.pos = P[s]; g.sP = SPs[s];
        g.nbr = nb; g.sN = SNB; g.pw1 = pos_w1 + (long)s*1152; g.pb1 = pos_b1 + (long)s*384;
        g.row0 = q0 * 16;
        mgemm_kernel<1, false, true, true><<<dim3(rows/64, 6, 4), 256, 0, stream>>>(g);
      }
      {
        GemmP g{}; g.A = db; g.sA = SCH; g.Wt = wt + (long)(4*4+s)*147456; g.bias = attn_b + (long)s*384;
        g.C = ab; g.sC = SCH; g.R = rows;
        g.nbr = nb; g.sN = SNB; g.adst = adb; g.sAD = SAD; g.asrc = asb; g.sAS = SV;
        g.row0 = q0 * 16;
        mgemm_kernel<2, false, true, true><<<dim3(rows/64, 6, 4), 256, 0, stream>>>(g);
      }
      attnln_kernel<<<dim3(Mc, 4), 128, 0, stream>>>(
          ab, db, vb, nb, vld, ln_g + (long)s*384, ln_b + (long)s*384,
          X[s+1], q0, SCH, SV, SNB, (long)M*384);
    }
  }

  feat_kernel<<<dim3(16, 4), 384, 0, stream>>>(x4, proj_w, proj_b, pln_g, pln_b, out + 192);
  tail_kernel<<<1, 256, 0, stream>>>(p4, out);
}

// Round 8
// 1467.035 us; speedup vs baseline: 1.1386x; 1.1386x over previous
//
#include <hip/hip_runtime.h>
#include <math.h>

// ---------------------------------------------------------------------------
// GlobalSceneEncoder: 4-stage point-transformer encoder.
// FPS/KNN: bit-exact f32 replication of the numpy reference (no FMA,
// fixed summation order), u32/u64 monotone-key reductions.
// FPS v6: fused update+tournament (12 ops/pt), DPP wave-max, LDS pos cache.
// GEMMs: f16 MFMA w/ fp32 accum. Everything else fp32.
// B=4, N0=4096, D=384, K=16.
// ---------------------------------------------------------------------------

using half8 = __attribute__((ext_vector_type(8))) _Float16;
using f32x4 = __attribute__((ext_vector_type(4))) float;

__device__ __forceinline__ float d2f(float ax, float ay, float az,
                                     float bx, float by, float bz)
{
  // exact np order: ((dx*dx + dy*dy) + dz*dz), no contraction
  const float dx = __fsub_rn(ax, bx);
  const float dy = __fsub_rn(ay, by);
  const float dz = __fsub_rn(az, bz);
  return __fadd_rn(__fadd_rn(__fmul_rn(dx, dx), __fmul_rn(dy, dy)),
                   __fmul_rn(dz, dz));
}

// ---- DPP u32 max reduce across wave64, result broadcast via readlane ------
template<int CTRL>
__device__ __forceinline__ unsigned dppmax_step(unsigned v)
{
  const unsigned o = (unsigned)__builtin_amdgcn_update_dpp(
      (int)v, (int)v, CTRL, 0xF, 0xF, false);
  return o > v ? o : v;
}
__device__ __forceinline__ unsigned wave_max_bcast(unsigned v)
{
  v = dppmax_step<0x111>(v);   // row_shr:1
  v = dppmax_step<0x112>(v);   // row_shr:2
  v = dppmax_step<0x114>(v);   // row_shr:4
  v = dppmax_step<0x118>(v);   // row_shr:8
  v = dppmax_step<0x142>(v);   // row_bcast:15
  v = dppmax_step<0x143>(v);   // row_bcast:31
  return (unsigned)__builtin_amdgcn_readlane((int)v, 63);
}

// ---------------- split pts -> pos0, x0 ----------------
__global__ __launch_bounds__(128) void split_kernel(
    const float* __restrict__ pts, float* __restrict__ pos0, float* __restrict__ x0)
{
  const int n = blockIdx.x;
  const int b = blockIdx.y;
  const float* src = pts + ((long)b * 4096 + n) * 387;
  float* pd = pos0 + ((long)b * 4096 + n) * 3;
  float* xd = x0 + ((long)b * 4096 + n) * 384;
  for (int e = threadIdx.x; e < 387; e += 128) {
    float v = src[e];
    if (e < 3) pd[e] = v; else xd[e - 3] = v;
  }
}

// ---------------- weight transpose + f16 convert: Wt[n][k] = W[k][n] -------
struct TP { const float* src[5]; _Float16* dst; };
__global__ __launch_bounds__(256) void transpose_kernel(TP p)
{
  const int z = blockIdx.z;
  const float* S = p.src[z >> 2] + (long)(z & 3) * 147456;
  _Float16* Dst = p.dst + (long)z * 147456;
  const int k0 = blockIdx.x * 32, n0 = blockIdx.y * 32;
  __shared__ float tile[32][33];
  const int ti = threadIdx.x & 31, tj = threadIdx.x >> 5;
  #pragma unroll
  for (int p8 = 0; p8 < 32; p8 += 8)
    tile[tj + p8][ti] = S[(long)(k0 + tj + p8) * 384 + n0 + ti];
  __syncthreads();
  #pragma unroll
  for (int p8 = 0; p8 < 32; p8 += 8)
    Dst[(long)(n0 + tj + p8) * 384 + k0 + ti] = (_Float16)tile[ti][tj + p8];
}

// ---------------- FPS v6: fused update+tournament, DPP reduce, LDS pos -----
// Contiguous ownership: thread t owns points [t*NPT, (t+1)*NPT) so
// lowest-lane tie-break == lowest-index tie-break.
template<int NPTS, int NTHR>
__global__ __launch_bounds__(NTHR, 1) void fps_kernel(
    const float* __restrict__ pos,
    int* __restrict__ idx_out, float* __restrict__ pos_out)
{
  constexpr int NPT = NPTS / NTHR;
  constexpr int NW = NTHR / 64;
  constexpr int M = NPTS / 4;
  const int b = blockIdx.x;
  pos += (long)b * NPTS * 3; idx_out += (long)b * M; pos_out += (long)b * M * 3;
  const int t = threadIdx.x;

  __shared__ float spx[NPTS], spy[NPTS], spz[NPTS];
  __shared__ unsigned long long s_key[2][NW > 1 ? NW : 1];

  float px[NPT], py[NPT], pz[NPT], dmin[NPT];
  #pragma unroll
  for (int i = 0; i < NPT; i++) {
    const int j = t * NPT + i;
    px[i] = pos[j*3]; py[i] = pos[j*3+1]; pz[i] = pos[j*3+2];
    spx[j] = px[i]; spy[j] = py[i]; spz[j] = pz[i];
  }
  const float sx = pos[0], sy = pos[1], sz = pos[2];
  // init distances + fused local tournament (ascending i, strict > keeps
  // the lowest local index on ties)
  float bv = 0.f; int bi = 0;
  #pragma unroll
  for (int i = 0; i < NPT; i++) {
    const float dd = d2f(px[i], py[i], pz[i], sx, sy, sz);
    dmin[i] = dd;
    if (i == 0) { bv = dd; bi = 0; }
    else { const bool g = dd > bv; bv = g ? dd : bv; bi = g ? i : bi; }
  }
  if (t == 0) { idx_out[0] = 0; pos_out[0] = sx; pos_out[1] = sy; pos_out[2] = sz; }
  if (NW > 1) __syncthreads();   // spx/spy/spz visible

  for (int m = 1; m < M; ++m) {
    // ---- wave max on u32 key (dmin >= 0 -> monotone bit pattern) ----
    const unsigned myub = __float_as_uint(bv);
    const unsigned wmax = wave_max_bcast(myub);
    const unsigned long long mk = __ballot(myub == wmax);
    const int srclane = __builtin_ctzll(mk);
    const int lbi = __shfl(bi, srclane);
    const int wj = ((t & ~63) + srclane) * NPT + lbi;   // wave winner, global

    int sel;
    if (NW > 1) {
      const int p = m & 1;
      if ((t & 63) == 0)
        s_key[p][t >> 6] =
            ((unsigned long long)wmax << 32) | (unsigned)(NPTS - 1 - wj);
      __syncthreads();
      unsigned long long kb = s_key[p][0];
      #pragma unroll
      for (int w2 = 1; w2 < NW; w2++) {
        const unsigned long long o = s_key[p][w2];
        if (o > kb) kb = o;
      }
      sel = NPTS - 1 - (int)(kb & 0xFFFFFFFFu);
    } else {
      sel = wj;
    }
    // ---- broadcast position lookup (same-address LDS reads) ----
    const float qx = spx[sel], qy = spy[sel], qz = spz[sel];
    if (t == 0) { idx_out[m] = sel; pos_out[m*3] = qx; pos_out[m*3+1] = qy; pos_out[m*3+2] = qz; }
    // ---- fused exact-f32 update + next tournament ----
    float nbv = 0.f; int nbi = 0;
    #pragma unroll
    for (int i = 0; i < NPT; i++) {
      const float dd = d2f(px[i], py[i], pz[i], qx, qy, qz);
      const float nd = fminf(dmin[i], dd);
      dmin[i] = nd;
      if (i == 0) { nbv = nd; nbi = 0; }
      else { const bool g = nd > nbv; nbv = g ? nd : nbv; nbi = g ? i : nbi; }
    }
    bv = nbv; bi = nbi;
  }
}

// ---------------- KNN: one wave/query, 16 passes, u64 (dist,j) keys --------
template<int C>
__global__ __launch_bounds__(64) void knn_kernel(
    const float* __restrict__ pos, const float* __restrict__ qpos,
    int N, int M, int* __restrict__ nbr, float* __restrict__ vld, float r2)
{
  const int m = blockIdx.x, b = blockIdx.y;
  pos += (long)b * N * 3; qpos += (long)b * M * 3;
  nbr += (long)b * (1024 * 16); vld += (long)b * (1024 * 16);
  const int lane = threadIdx.x;
  const float qx = qpos[m*3], qy = qpos[m*3+1], qz = qpos[m*3+2];
  unsigned long long key[C];
  #pragma unroll
  for (int c = 0; c < C; c++) {
    const int j = c * 64 + lane;
    const float dd = d2f(pos[j*3], pos[j*3+1], pos[j*3+2], qx, qy, qz);
    key[c] = ((unsigned long long)__float_as_uint(dd) << 32) | (unsigned)j;
  }
  unsigned long long prev = 0;
  for (int k = 0; k < 16; k++) {
    unsigned long long best = ~0ull;
    #pragma unroll
    for (int c = 0; c < C; c++) {
      const bool take = (k == 0) || (key[c] > prev);
      if (take && key[c] < best) best = key[c];
    }
    #pragma unroll
    for (int off = 32; off; off >>= 1) {
      const unsigned long long o = __shfl_xor(best, off);
      if (o < best) best = o;
    }
    prev = best;
    if (lane == 0) {
      nbr[m*16+k] = (int)(best & 0xFFFFFFFFu);
      const float dd = __uint_as_float((unsigned)(best >> 32));
      vld[m*16+k] = (dd <= r2) ? 1.0f : 0.0f;
    }
  }
}

// ---------------- f16 MFMA GEMM, 64x64 tile, BK=32, 3 A-operand modes ------
struct GemmP {
  const float* A; long sA;
  const _Float16* Wt;          // pre-transposed f16 weights: Wt[n][k]
  const float* bias;
  float* C; long sC;
  int R;
  const int* gather; long sG;
  const float* qpos; long sQ;
  const float* pos;  long sP;
  const int* nbr;    long sN;
  const float* pw1;
  const float* pb1;
  const float* adst; long sAD;
  const float* asrc; long sAS;
  int row0;
};

template<int AMODE, bool GATHER, bool BIAS, bool RELU>
__global__ __launch_bounds__(256) void mgemm_kernel(GemmP p)
{
  const int b = blockIdx.z;
  const int rb = blockIdx.x * 64;
  const int cb = blockIdx.y * 64;
  const int t = threadIdx.x;
  const float* A = p.A ? (p.A + (long)b * p.sA) : nullptr;
  float* C = p.C + (long)b * p.sC;
  const int* gat = GATHER ? (p.gather + (long)b * p.sG) : nullptr;
  const int* nbrb = (AMODE != 0) ? (p.nbr + (long)b * p.sN) : nullptr;

  __shared__ _Float16 As[64][40];
  __shared__ _Float16 Bs[64][40];

  const int w = t >> 6, lane = t & 63;
  const int wm = w & 1, wn = w >> 1;
  const int quad = lane >> 4, l16 = lane & 15;

  f32x4 acc[2][2] = {};

  const int sr = t >> 2;
  const int sk = (t & 3) << 3;
  const int ar = rb + sr;

  const float* arow = nullptr;
  const float* adrow = nullptr;
  const float* asrow = nullptr;
  bool avalid = true;
  float rx = 0.f, ry = 0.f, rz = 0.f;
  if (AMODE == 0) {
    avalid = (ar < p.R);
    long srcrow = 0;
    if (avalid) srcrow = GATHER ? (long)gat[ar] : (long)ar;
    arow = A + srcrow * 384;
  } else {
    const int grow = p.row0 + ar;
    const int mq = grow >> 4;
    const int n = nbrb[grow];
    if (AMODE == 1) {
      const float* qposb = p.qpos + (long)b * p.sQ;
      const float* posb = p.pos + (long)b * p.sP;
      rx = qposb[mq*3+0] - posb[n*3+0];
      ry = qposb[mq*3+1] - posb[n*3+1];
      rz = qposb[mq*3+2] - posb[n*3+2];
    } else {
      arow = A + (long)ar * 384;
      adrow = p.adst + (long)b * p.sAD + (long)mq * 384;
      asrow = p.asrc + (long)b * p.sAS + (long)n * 384;
    }
  }

  for (int k0 = 0; k0 < 384; k0 += 32) {
    float a8[8];
    if (AMODE == 0) {
      if (avalid) {
        const float4 u = *(const float4*)(arow + k0 + sk);
        const float4 v = *(const float4*)(arow + k0 + sk + 4);
        a8[0]=u.x; a8[1]=u.y; a8[2]=u.z; a8[3]=u.w;
        a8[4]=v.x; a8[5]=v.y; a8[6]=v.z; a8[7]=v.w;
      } else {
        #pragma unroll
        for (int j = 0; j < 8; j++) a8[j] = 0.f;
      }
    } else if (AMODE == 1) {
      const int kc = k0 + sk;
      const float4 w0a = *(const float4*)(p.pw1 + kc);
      const float4 w0b = *(const float4*)(p.pw1 + kc + 4);
      const float4 w1a = *(const float4*)(p.pw1 + 384 + kc);
      const float4 w1b = *(const float4*)(p.pw1 + 384 + kc + 4);
      const float4 w2a = *(const float4*)(p.pw1 + 768 + kc);
      const float4 w2b = *(const float4*)(p.pw1 + 768 + kc + 4);
      const float4 b1a = *(const float4*)(p.pb1 + kc);
      const float4 b1b = *(const float4*)(p.pb1 + kc + 4);
      a8[0] = fmaxf(rx*w0a.x + ry*w1a.x + rz*w2a.x + b1a.x, 0.f);
      a8[1] = fmaxf(rx*w0a.y + ry*w1a.y + rz*w2a.y + b1a.y, 0.f);
      a8[2] = fmaxf(rx*w0a.z + ry*w1a.z + rz*w2a.z + b1a.z, 0.f);
      a8[3] = fmaxf(rx*w0a.w + ry*w1a.w + rz*w2a.w + b1a.w, 0.f);
      a8[4] = fmaxf(rx*w0b.x + ry*w1b.x + rz*w2b.x + b1b.x, 0.f);
      a8[5] = fmaxf(rx*w0b.y + ry*w1b.y + rz*w2b.y + b1b.y, 0.f);
      a8[6] = fmaxf(rx*w0b.z + ry*w1b.z + rz*w2b.z + b1b.z, 0.f);
      a8[7] = fmaxf(rx*w0b.w + ry*w1b.w + rz*w2b.w + b1b.w, 0.f);
    } else {
      const int kc = k0 + sk;
      const float4 d0 = *(const float4*)(arow + kc);
      const float4 d1 = *(const float4*)(arow + kc + 4);
      const float4 a0 = *(const float4*)(adrow + kc);
      const float4 a1 = *(const float4*)(adrow + kc + 4);
      const float4 s0 = *(const float4*)(asrow + kc);
      const float4 s1 = *(const float4*)(asrow + kc + 4);
      a8[0] = a0.x - s0.x + d0.x; a8[1] = a0.y - s0.y + d0.y;
      a8[2] = a0.z - s0.z + d0.z; a8[3] = a0.w - s0.w + d0.w;
      a8[4] = a1.x - s1.x + d1.x; a8[5] = a1.y - s1.y + d1.y;
      a8[6] = a1.z - s1.z + d1.z; a8[7] = a1.w - s1.w + d1.w;
    }
    const half8 bv = *(const half8*)(p.Wt + (long)(cb + sr) * 384 + k0 + sk);

    __syncthreads();
    half8 av;
    #pragma unroll
    for (int j = 0; j < 8; j++) av[j] = (_Float16)a8[j];
    *(half8*)&As[sr][sk] = av;
    *(half8*)&Bs[sr][sk] = bv;
    __syncthreads();

    const half8 fa0 = *(const half8*)&As[wm*32 + l16][quad*8];
    const half8 fa1 = *(const half8*)&As[wm*32 + 16 + l16][quad*8];
    const half8 fb0 = *(const half8*)&Bs[wn*32 + l16][quad*8];
    const half8 fb1 = *(const half8*)&Bs[wn*32 + 16 + l16][quad*8];
    acc[0][0] = __builtin_amdgcn_mfma_f32_16x16x32_f16(fa0, fb0, acc[0][0], 0, 0, 0);
    acc[0][1] = __builtin_amdgcn_mfma_f32_16x16x32_f16(fa0, fb1, acc[0][1], 0, 0, 0);
    acc[1][0] = __builtin_amdgcn_mfma_f32_16x16x32_f16(fa1, fb0, acc[1][0], 0, 0, 0);
    acc[1][1] = __builtin_amdgcn_mfma_f32_16x16x32_f16(fa1, fb1, acc[1][1], 0, 0, 0);
  }

  float bi0 = 0.f, bi1 = 0.f;
  if (BIAS) {
    bi0 = p.bias[cb + wn*32 + l16];
    bi1 = p.bias[cb + wn*32 + 16 + l16];
  }
  #pragma unroll
  for (int i = 0; i < 2; i++) {
    const int base = rb + wm*32 + i*16;
    if (base < p.R) {
      const int r0 = base + quad*4;
      #pragma unroll
      for (int j = 0; j < 2; j++) {
        const int col = cb + wn*32 + j*16 + l16;
        const float bb = j ? bi1 : bi0;
        #pragma unroll
        for (int reg = 0; reg < 4; reg++) {
          float v = acc[i][j][reg] + bb;
          if (RELU) v = fmaxf(v, 0.f);
          C[(long)(r0 + reg) * 384 + col] = v;
        }
      }
    }
  }
}

// ---------------- masked softmax over K + weighted sum + LayerNorm ---------
__global__ __launch_bounds__(128) void attnln_kernel(
    const float* __restrict__ alpha, const float* __restrict__ delta,
    const float* __restrict__ vbuf, const int* __restrict__ nbr,
    const float* __restrict__ vldb, const float* __restrict__ lng,
    const float* __restrict__ lnb, float* __restrict__ xout,
    int q0, long sCh, long sV, long sNb, long sX)
{
  const int ml = blockIdx.x, b = blockIdx.y;
  const int m = q0 + ml;
  alpha += (long)b * sCh; delta += (long)b * sCh; vbuf += (long)b * sV;
  nbr += (long)b * sNb; vldb += (long)b * sNb; xout += (long)b * sX;
  const int t = threadIdx.x;

  int nb[16]; float vl[16];
  #pragma unroll
  for (int k = 0; k < 16; k++) { nb[k] = nbr[m*16+k]; vl[k] = vldb[m*16+k]; }

  const long rbase = (long)ml * 16 * 384;
  float av[16][3];
  #pragma unroll
  for (int k = 0; k < 16; k++)
    #pragma unroll
    for (int i = 0; i < 3; i++) {
      const float a = alpha[rbase + k*384 + t + i*128];
      av[k][i] = (vl[k] > 0.5f) ? a : -1e30f;
    }
  float mx[3] = {-3.4e38f, -3.4e38f, -3.4e38f};
  #pragma unroll
  for (int k = 0; k < 16; k++)
    #pragma unroll
    for (int i = 0; i < 3; i++) mx[i] = fmaxf(mx[i], av[k][i]);
  float sm[3] = {0.f, 0.f, 0.f};
  #pragma unroll
  for (int k = 0; k < 16; k++)
    #pragma unroll
    for (int i = 0; i < 3; i++) { const float e = expf(av[k][i] - mx[i]); av[k][i] = e; sm[i] += e; }
  float rs[3];
  #pragma unroll
  for (int i = 0; i < 3; i++) rs[i] = 1.0f / sm[i];
  float o[3] = {0.f, 0.f, 0.f};
  #pragma unroll
  for (int k = 0; k < 16; k++) {
    const long nrow = (long)nb[k] * 384;
    #pragma unroll
    for (int i = 0; i < 3; i++) {
      const int dd = t + i * 128;
      const float vv = vbuf[nrow + dd] + delta[rbase + k*384 + dd];
      o[i] += (av[k][i] * rs[i] * vl[k]) * vv;
    }
  }
  __shared__ float sred[2];
  float s1 = o[0] + o[1] + o[2];
  #pragma unroll
  for (int off = 32; off; off >>= 1) s1 += __shfl_xor(s1, off);
  if ((t & 63) == 0) sred[t >> 6] = s1;
  __syncthreads();
  const float mean = (sred[0] + sred[1]) * (1.0f / 384.0f);
  __syncthreads();
  float s2 = 0.f;
  #pragma unroll
  for (int i = 0; i < 3; i++) { const float dd = o[i] - mean; s2 += dd * dd; }
  #pragma unroll
  for (int off = 32; off; off >>= 1) s2 += __shfl_xor(s2, off);
  if ((t & 63) == 0) sred[t >> 6] = s2;
  __syncthreads();
  const float var = (sred[0] + sred[1]) * (1.0f / 384.0f);
  const float rstd = 1.0f / sqrtf(var + 1e-5f);
  #pragma unroll
  for (int i = 0; i < 3; i++) {
    const int dd = t + i * 128;
    xout[(long)m * 384 + dd] = (o[i] - mean) * rstd * lng[dd] + lnb[dd];
  }
}

// ---------------- final projection + LayerNorm -----------------------------
__global__ __launch_bounds__(384) void feat_kernel(
    const float* __restrict__ x4, const float* __restrict__ pw,
    const float* __restrict__ pb, const float* __restrict__ g,
    const float* __restrict__ be, float* __restrict__ outf)
{
  const int row = blockIdx.x, b = blockIdx.y;
  const long r = (long)b * 16 + row;
  const int d = threadIdx.x;
  __shared__ float xs[384];
  xs[d] = x4[r * 384 + d];
  __syncthreads();
  float acc = pb[d];
  #pragma unroll 8
  for (int j = 0; j < 384; j++) acc = fmaf(xs[j], pw[(long)j * 384 + d], acc);
  __shared__ float sred[6];
  float s = acc;
  #pragma unroll
  for (int off = 32; off; off >>= 1) s += __shfl_xor(s, off);
  if ((d & 63) == 0) sred[d >> 6] = s;
  __syncthreads();
  const float mean = (sred[0]+sred[1]+sred[2]+sred[3]+sred[4]+sred[5]) * (1.0f/384.0f);
  __syncthreads();
  float dv = (acc - mean) * (acc - mean);
  #pragma unroll
  for (int off = 32; off; off >>= 1) dv += __shfl_xor(dv, off);
  if ((d & 63) == 0) sred[d >> 6] = dv;
  __syncthreads();
  const float var = (sred[0]+sred[1]+sred[2]+sred[3]+sred[4]+sred[5]) * (1.0f/384.0f);
  const float rstd = 1.0f / sqrtf(var + 1e-5f);
  outf[r * 384 + d] = (acc - mean) * rstd * g[d] + be[d];
}

// ---------------- pos + pad outputs ----------------------------------------
__global__ void tail_kernel(const float* __restrict__ p4, float* __restrict__ out)
{
  const int t = threadIdx.x;
  if (t < 192) out[t] = p4[t];
  if (t < 64) out[192 + 24576 + t] = 0.0f;
}

// ---------------------------------------------------------------------------
extern "C" void kernel_launch(void* const* d_in, const int* in_sizes, int n_in,
                              void* d_out, int out_size, void* d_ws, size_t ws_size,
                              hipStream_t stream)
{
  (void)in_sizes; (void)n_in; (void)out_size; (void)ws_size;
  const float* pts    = (const float*)d_in[0];
  const float* lin_w  = (const float*)d_in[1];
  const float* lin_b  = (const float*)d_in[2];
  const float* src_w  = (const float*)d_in[3];
  const float* dst_w  = (const float*)d_in[4];
  const float* pos_w1 = (const float*)d_in[5];
  const float* pos_b1 = (const float*)d_in[6];
  const float* pos_w2 = (const float*)d_in[7];
  const float* pos_b2 = (const float*)d_in[8];
  const float* attn_w = (const float*)d_in[9];
  const float* attn_b = (const float*)d_in[10];
  const float* ln_g   = (const float*)d_in[11];
  const float* ln_b   = (const float*)d_in[12];
  const float* proj_w = (const float*)d_in[13];
  const float* proj_b = (const float*)d_in[14];
  const float* pln_g  = (const float*)d_in[15];
  const float* pln_b  = (const float*)d_in[16];
  float* out = (float*)d_out;

  // ---- workspace layout (R5-proven, chunked) ----
  constexpr long SX0 = 4096L*384, SX1 = 1024L*384, SX2 = 256L*384, SX3 = 64L*384, SX4 = 16L*384;
  constexpr long SP0 = 4096L*3, SP1 = 1024L*3, SP2 = 256L*3, SP3 = 64L*3, SP4 = 16L*3;
  constexpr long SV  = 4096L*384;
  constexpr long SAD = 1024L*384;
  constexpr long SCH = 4096L*384;
  constexpr long SNB = 1024L*16;

  _Float16* wt = (_Float16*)d_ws;
  float* ws = (float*)(wt + 20L * 147456);
  float* x0 = ws; ws += 4*SX0;
  float* x1 = ws; ws += 4*SX1;
  float* x2 = ws; ws += 4*SX2;
  float* x3 = ws; ws += 4*SX3;
  float* x4 = ws; ws += 4*SX4;
  float* p0 = ws; ws += 4*SP0;
  float* p1 = ws; ws += 4*SP1;
  float* p2 = ws; ws += 4*SP2;
  float* p3 = ws; ws += 4*SP3;
  float* p4 = ws; ws += 4*SP4;
  float* vb = ws; ws += 4*SV;
  float* asb = ws; ws += 4*SV;
  float* adb = ws; ws += 4*SAD;
  float* db = ws; ws += 4*SCH;
  float* ab = ws; ws += 4*SCH;
  float* vld = ws; ws += 4*SNB;
  int* nb = (int*)ws; ws += 4*SNB;
  int* ix[4];
  ix[0] = (int*)ws; ws += 4*1024;
  ix[1] = (int*)ws; ws += 4*256;
  ix[2] = (int*)ws; ws += 4*64;
  ix[3] = (int*)ws; ws += 4*16;

  const int Ns[4] = {4096, 1024, 256, 64};
  const int Ms[4] = {1024, 256, 64, 16};
  const float R2[4] = {1.0f, 4.0f, 16.0f, 64.0f};
  float* X[5] = {x0, x1, x2, x3, x4};
  float* P[5] = {p0, p1, p2, p3, p4};
  long SPs[5] = {SP0, SP1, SP2, SP3, SP4};
  long SXs[5] = {SX0, SX1, SX2, SX3, SX4};

  split_kernel<<<dim3(4096, 4), 128, 0, stream>>>(pts, p0, x0);

  {
    TP tp{};
    tp.src[0] = lin_w; tp.src[1] = src_w; tp.src[2] = dst_w;
    tp.src[3] = pos_w2; tp.src[4] = attn_w;
    tp.dst = wt;
    transpose_kernel<<<dim3(12, 12, 20), 256, 0, stream>>>(tp);
  }

  // FPS chain (v6)
  fps_kernel<4096, 256><<<dim3(4), 256, 0, stream>>>(P[0], ix[0], P[1]);
  fps_kernel<1024, 256><<<dim3(4), 256, 0, stream>>>(P[1], ix[1], P[2]);
  fps_kernel<256, 64><<<dim3(4), 64, 0, stream>>>(P[2], ix[2], P[3]);
  fps_kernel<64, 64><<<dim3(4), 64, 0, stream>>>(P[3], ix[3], P[4]);

  for (int s = 0; s < 4; s++) {
    const int N = Ns[s], M = Ms[s];
    switch (s) {
      case 0: knn_kernel<64><<<dim3(M, 4), 64, 0, stream>>>(P[s], P[s+1], N, M, nb, vld, R2[s]); break;
      case 1: knn_kernel<16><<<dim3(M, 4), 64, 0, stream>>>(P[s], P[s+1], N, M, nb, vld, R2[s]); break;
      case 2: knn_kernel<4><<<dim3(M, 4), 64, 0, stream>>>(P[s], P[s+1], N, M, nb, vld, R2[s]); break;
      default: knn_kernel<1><<<dim3(M, 4), 64, 0, stream>>>(P[s], P[s+1], N, M, nb, vld, R2[s]); break;
    }
    // v = x@lw + lb
    {
      GemmP g{}; g.A = X[s]; g.sA = SXs[s]; g.Wt = wt + (long)(0*4+s)*147456; g.bias = lin_b + (long)s*384;
      g.C = vb; g.sC = SV; g.R = N;
      mgemm_kernel<0, false, true, false><<<dim3(N/64, 6, 4), 256, 0, stream>>>(g);
    }
    // a_src = x@sw
    {
      GemmP g{}; g.A = X[s]; g.sA = SXs[s]; g.Wt = wt + (long)(1*4+s)*147456;
      g.C = asb; g.sC = SV; g.R = N;
      mgemm_kernel<0, false, false, false><<<dim3(N/64, 6, 4), 256, 0, stream>>>(g);
    }
    // a_dst = x[idx]@dw
    {
      GemmP g{}; g.A = X[s]; g.sA = SXs[s]; g.Wt = wt + (long)(2*4+s)*147456;
      g.C = adb; g.sC = SAD; g.R = M; g.gather = ix[s]; g.sG = M;
      mgemm_kernel<0, true, false, false><<<dim3((M+63)/64, 6, 4), 256, 0, stream>>>(g);
    }
    const int nch = (M + 255) / 256;
    for (int c = 0; c < nch; c++) {
      const int q0 = c * 256;
      const int Mc = (M - q0 < 256) ? (M - q0) : 256;
      const int rows = Mc * 16;
      {
        GemmP g{}; g.Wt = wt + (long)(3*4+s)*147456; g.bias = pos_b2 + (long)s*384;
        g.C = db; g.sC = SCH; g.R = rows;
        g.qpos = P[s+1]; g.sQ = SPs[s+1]; g.pos = P[s]; g.sP = SPs[s];
        g.nbr = nb; g.sN = SNB; g.pw1 = pos_w1 + (long)s*1152; g.pb1 = pos_b1 + (long)s*384;
        g.row0 = q0 * 16;
        mgemm_kernel<1, false, true, true><<<dim3(rows/64, 6, 4), 256, 0, stream>>>(g);
      }
      {
        GemmP g{}; g.A = db; g.sA = SCH; g.Wt = wt + (long)(4*4+s)*147456; g.bias = attn_b + (long)s*384;
        g.C = ab; g.sC = SCH; g.R = rows;
        g.nbr = nb; g.sN = SNB; g.adst = adb; g.sAD = SAD; g.asrc = asb; g.sAS = SV;
        g.row0 = q0 * 16;
        mgemm_kernel<2, false, true, true><<<dim3(rows/64, 6, 4), 256, 0, stream>>>(g);
      }
      attnln_kernel<<<dim3(Mc, 4), 128, 0, stream>>>(
          ab, db, vb, nb, vld, ln_g + (long)s*384, ln_b + (long)s*384,
          X[s+1], q0, SCH, SV, SNB, (long)M*384);
    }
  }

  feat_kernel<<<dim3(16, 4), 384, 0, stream>>>(x4, proj_w, proj_b, pln_g, pln_b, out + 192);
  tail_kernel<<<1, 256, 0, stream>>>(p4, out);
}

// Round 9
// 1458.232 us; speedup vs baseline: 1.1455x; 1.0060x over previous
//
#include <hip/hip_runtime.h>
#include <math.h>

// ---------------------------------------------------------------------------
// GlobalSceneEncoder: 4-stage point-transformer encoder.
// FPS/KNN: bit-exact f32 replication of the numpy reference (no FMA,
// fixed summation order), u32/u64 monotone-key reductions.
// FPS v6: fused update+tournament (12 ops/pt), DPP wave-max, LDS pos cache.
// GEMMs: f16 MFMA w/ fp32 accum. fat1 = fps0 || v0 || a_src0 overlap.
// B=4, N0=4096, D=384, K=16.
// ---------------------------------------------------------------------------

using half8 = __attribute__((ext_vector_type(8))) _Float16;
using f32x4 = __attribute__((ext_vector_type(4))) float;

__device__ __forceinline__ float d2f(float ax, float ay, float az,
                                     float bx, float by, float bz)
{
  // exact np order: ((dx*dx + dy*dy) + dz*dz), no contraction
  const float dx = __fsub_rn(ax, bx);
  const float dy = __fsub_rn(ay, by);
  const float dz = __fsub_rn(az, bz);
  return __fadd_rn(__fadd_rn(__fmul_rn(dx, dx), __fmul_rn(dy, dy)),
                   __fmul_rn(dz, dz));
}

// ---- DPP u32 max reduce across wave64, result broadcast via readlane ------
template<int CTRL>
__device__ __forceinline__ unsigned dppmax_step(unsigned v)
{
  const unsigned o = (unsigned)__builtin_amdgcn_update_dpp(
      (int)v, (int)v, CTRL, 0xF, 0xF, false);
  return o > v ? o : v;
}
__device__ __forceinline__ unsigned wave_max_bcast(unsigned v)
{
  v = dppmax_step<0x111>(v);   // row_shr:1
  v = dppmax_step<0x112>(v);   // row_shr:2
  v = dppmax_step<0x114>(v);   // row_shr:4
  v = dppmax_step<0x118>(v);   // row_shr:8
  v = dppmax_step<0x142>(v);   // row_bcast:15
  v = dppmax_step<0x143>(v);   // row_bcast:31
  return (unsigned)__builtin_amdgcn_readlane((int)v, 63);
}

// ---------------- split pts -> pos0, x0 ----------------
__global__ __launch_bounds__(128) void split_kernel(
    const float* __restrict__ pts, float* __restrict__ pos0, float* __restrict__ x0)
{
  const int n = blockIdx.x;
  const int b = blockIdx.y;
  const float* src = pts + ((long)b * 4096 + n) * 387;
  float* pd = pos0 + ((long)b * 4096 + n) * 3;
  float* xd = x0 + ((long)b * 4096 + n) * 384;
  for (int e = threadIdx.x; e < 387; e += 128) {
    float v = src[e];
    if (e < 3) pd[e] = v; else xd[e - 3] = v;
  }
}

// ---------------- weight transpose + f16 convert: Wt[n][k] = W[k][n] -------
struct TP { const float* src[5]; _Float16* dst; };
__global__ __launch_bounds__(256) void transpose_kernel(TP p)
{
  const int z = blockIdx.z;
  const float* S = p.src[z >> 2] + (long)(z & 3) * 147456;
  _Float16* Dst = p.dst + (long)z * 147456;
  const int k0 = blockIdx.x * 32, n0 = blockIdx.y * 32;
  __shared__ float tile[32][33];
  const int ti = threadIdx.x & 31, tj = threadIdx.x >> 5;
  #pragma unroll
  for (int p8 = 0; p8 < 32; p8 += 8)
    tile[tj + p8][ti] = S[(long)(k0 + tj + p8) * 384 + n0 + ti];
  __syncthreads();
  #pragma unroll
  for (int p8 = 0; p8 < 32; p8 += 8)
    Dst[(long)(n0 + tj + p8) * 384 + k0 + ti] = (_Float16)tile[ti][tj + p8];
}

// ---------------- FPS v6 body: fused update+tournament, DPP reduce ---------
// Contiguous ownership: thread t owns points [t*NPT, (t+1)*NPT) so
// lowest-lane tie-break == lowest-index tie-break.
template<int NPTS, int NTHR>
__device__ __forceinline__ void fps_body(
    const float* __restrict__ pos,
    int* __restrict__ idx_out, float* __restrict__ pos_out,
    int b, int t,
    float* __restrict__ spx, float* __restrict__ spy, float* __restrict__ spz,
    unsigned long long* __restrict__ s_key)
{
  constexpr int NPT = NPTS / NTHR;
  constexpr int NW = NTHR / 64;
  constexpr int M = NPTS / 4;
  pos += (long)b * NPTS * 3; idx_out += (long)b * M; pos_out += (long)b * M * 3;

  float px[NPT], py[NPT], pz[NPT], dmin[NPT];
  #pragma unroll
  for (int i = 0; i < NPT; i++) {
    const int j = t * NPT + i;
    px[i] = pos[j*3]; py[i] = pos[j*3+1]; pz[i] = pos[j*3+2];
    spx[j] = px[i]; spy[j] = py[i]; spz[j] = pz[i];
  }
  const float sx = pos[0], sy = pos[1], sz = pos[2];
  float bv = 0.f; int bi = 0;
  #pragma unroll
  for (int i = 0; i < NPT; i++) {
    const float dd = d2f(px[i], py[i], pz[i], sx, sy, sz);
    dmin[i] = dd;
    if (i == 0) { bv = dd; bi = 0; }
    else { const bool g = dd > bv; bv = g ? dd : bv; bi = g ? i : bi; }
  }
  if (t == 0) { idx_out[0] = 0; pos_out[0] = sx; pos_out[1] = sy; pos_out[2] = sz; }
  if (NW > 1) __syncthreads();   // spx/spy/spz visible

  for (int m = 1; m < M; ++m) {
    const unsigned myub = __float_as_uint(bv);
    const unsigned wmax = wave_max_bcast(myub);
    const unsigned long long mk = __ballot(myub == wmax);
    const int srclane = __builtin_ctzll(mk);
    const int lbi = __shfl(bi, srclane);
    const int wj = ((t & ~63) + srclane) * NPT + lbi;   // wave winner, global

    int sel;
    if (NW > 1) {
      const int p = m & 1;
      if ((t & 63) == 0)
        s_key[p*NW + (t >> 6)] =
            ((unsigned long long)wmax << 32) | (unsigned)(NPTS - 1 - wj);
      __syncthreads();
      unsigned long long kb = s_key[p*NW];
      #pragma unroll
      for (int w2 = 1; w2 < NW; w2++) {
        const unsigned long long o = s_key[p*NW + w2];
        if (o > kb) kb = o;
      }
      sel = NPTS - 1 - (int)(kb & 0xFFFFFFFFu);
    } else {
      sel = wj;
    }
    const float qx = spx[sel], qy = spy[sel], qz = spz[sel];
    if (t == 0) { idx_out[m] = sel; pos_out[m*3] = qx; pos_out[m*3+1] = qy; pos_out[m*3+2] = qz; }
    float nbv = 0.f; int nbi = 0;
    #pragma unroll
    for (int i = 0; i < NPT; i++) {
      const float dd = d2f(px[i], py[i], pz[i], qx, qy, qz);
      const float nd = fminf(dmin[i], dd);
      dmin[i] = nd;
      if (i == 0) { nbv = nd; nbi = 0; }
      else { const bool g = nd > nbv; nbv = g ? nd : nbv; nbi = g ? i : nbi; }
    }
    bv = nbv; bi = nbi;
  }
}

template<int NPTS, int NTHR>
__global__ __launch_bounds__(NTHR, 1) void fps_kernel(
    const float* __restrict__ pos,
    int* __restrict__ idx_out, float* __restrict__ pos_out)
{
  __shared__ float spx[NPTS], spy[NPTS], spz[NPTS];
  __shared__ unsigned long long s_key[2 * (NTHR > 64 ? NTHR / 64 : 1)];
  fps_body<NPTS, NTHR>(pos, idx_out, pos_out, blockIdx.x, threadIdx.x,
                       spx, spy, spz, s_key);
}

// ---------------- KNN: one wave/query, 16 passes, u64 (dist,j) keys --------
template<int C>
__global__ __launch_bounds__(64) void knn_kernel(
    const float* __restrict__ pos, const float* __restrict__ qpos,
    int N, int M, int* __restrict__ nbr, float* __restrict__ vld, float r2)
{
  const int m = blockIdx.x, b = blockIdx.y;
  pos += (long)b * N * 3; qpos += (long)b * M * 3;
  nbr += (long)b * (1024 * 16); vld += (long)b * (1024 * 16);
  const int lane = threadIdx.x;
  const float qx = qpos[m*3], qy = qpos[m*3+1], qz = qpos[m*3+2];
  unsigned long long key[C];
  #pragma unroll
  for (int c = 0; c < C; c++) {
    const int j = c * 64 + lane;
    const float dd = d2f(pos[j*3], pos[j*3+1], pos[j*3+2], qx, qy, qz);
    key[c] = ((unsigned long long)__float_as_uint(dd) << 32) | (unsigned)j;
  }
  unsigned long long prev = 0;
  for (int k = 0; k < 16; k++) {
    unsigned long long best = ~0ull;
    #pragma unroll
    for (int c = 0; c < C; c++) {
      const bool take = (k == 0) || (key[c] > prev);
      if (take && key[c] < best) best = key[c];
    }
    #pragma unroll
    for (int off = 32; off; off >>= 1) {
      const unsigned long long o = __shfl_xor(best, off);
      if (o < best) best = o;
    }
    prev = best;
    if (lane == 0) {
      nbr[m*16+k] = (int)(best & 0xFFFFFFFFu);
      const float dd = __uint_as_float((unsigned)(best >> 32));
      vld[m*16+k] = (dd <= r2) ? 1.0f : 0.0f;
    }
  }
}

// ---------------- f16 MFMA GEMM body, 64x64 tile, BK=32 --------------------
struct GemmP {
  const float* A; long sA;
  const _Float16* Wt;          // pre-transposed f16 weights: Wt[n][k]
  const float* bias;
  float* C; long sC;
  int R;
  const int* gather; long sG;
  const float* qpos; long sQ;
  const float* pos;  long sP;
  const int* nbr;    long sN;
  const float* pw1;
  const float* pb1;
  const float* adst; long sAD;
  const float* asrc; long sAS;
  int row0;
};

typedef _Float16 (*H40)[40];

template<int AMODE, bool GATHER, bool BIAS, bool RELU>
__device__ __forceinline__ void mgemm_body(
    const GemmP& p, int bx, int by, int bz, int t, H40 As, H40 Bs)
{
  const int b = bz;
  const int rb = bx * 64;
  const int cb = by * 64;
  const float* A = p.A ? (p.A + (long)b * p.sA) : nullptr;
  float* C = p.C + (long)b * p.sC;
  const int* gat = GATHER ? (p.gather + (long)b * p.sG) : nullptr;
  const int* nbrb = (AMODE != 0) ? (p.nbr + (long)b * p.sN) : nullptr;

  const int w = t >> 6, lane = t & 63;
  const int wm = w & 1, wn = w >> 1;
  const int quad = lane >> 4, l16 = lane & 15;

  f32x4 acc[2][2] = {};

  const int sr = t >> 2;
  const int sk = (t & 3) << 3;
  const int ar = rb + sr;

  const float* arow = nullptr;
  const float* adrow = nullptr;
  const float* asrow = nullptr;
  bool avalid = true;
  float rx = 0.f, ry = 0.f, rz = 0.f;
  if (AMODE == 0) {
    avalid = (ar < p.R);
    long srcrow = 0;
    if (avalid) srcrow = GATHER ? (long)gat[ar] : (long)ar;
    arow = A + srcrow * 384;
  } else {
    const int grow = p.row0 + ar;
    const int mq = grow >> 4;
    const int n = nbrb[grow];
    if (AMODE == 1) {
      const float* qposb = p.qpos + (long)b * p.sQ;
      const float* posb = p.pos + (long)b * p.sP;
      rx = qposb[mq*3+0] - posb[n*3+0];
      ry = qposb[mq*3+1] - posb[n*3+1];
      rz = qposb[mq*3+2] - posb[n*3+2];
    } else {
      arow = A + (long)ar * 384;
      adrow = p.adst + (long)b * p.sAD + (long)mq * 384;
      asrow = p.asrc + (long)b * p.sAS + (long)n * 384;
    }
  }

  for (int k0 = 0; k0 < 384; k0 += 32) {
    float a8[8];
    if (AMODE == 0) {
      if (avalid) {
        const float4 u = *(const float4*)(arow + k0 + sk);
        const float4 v = *(const float4*)(arow + k0 + sk + 4);
        a8[0]=u.x; a8[1]=u.y; a8[2]=u.z; a8[3]=u.w;
        a8[4]=v.x; a8[5]=v.y; a8[6]=v.z; a8[7]=v.w;
      } else {
        #pragma unroll
        for (int j = 0; j < 8; j++) a8[j] = 0.f;
      }
    } else if (AMODE == 1) {
      const int kc = k0 + sk;
      const float4 w0a = *(const float4*)(p.pw1 + kc);
      const float4 w0b = *(const float4*)(p.pw1 + kc + 4);
      const float4 w1a = *(const float4*)(p.pw1 + 384 + kc);
      const float4 w1b = *(const float4*)(p.pw1 + 384 + kc + 4);
      const float4 w2a = *(const float4*)(p.pw1 + 768 + kc);
      const float4 w2b = *(const float4*)(p.pw1 + 768 + kc + 4);
      const float4 b1a = *(const float4*)(p.pb1 + kc);
      const float4 b1b = *(const float4*)(p.pb1 + kc + 4);
      a8[0] = fmaxf(rx*w0a.x + ry*w1a.x + rz*w2a.x + b1a.x, 0.f);
      a8[1] = fmaxf(rx*w0a.y + ry*w1a.y + rz*w2a.y + b1a.y, 0.f);
      a8[2] = fmaxf(rx*w0a.z + ry*w1a.z + rz*w2a.z + b1a.z, 0.f);
      a8[3] = fmaxf(rx*w0a.w + ry*w1a.w + rz*w2a.w + b1a.w, 0.f);
      a8[4] = fmaxf(rx*w0b.x + ry*w1b.x + rz*w2b.x + b1b.x, 0.f);
      a8[5] = fmaxf(rx*w0b.y + ry*w1b.y + rz*w2b.y + b1b.y, 0.f);
      a8[6] = fmaxf(rx*w0b.z + ry*w1b.z + rz*w2b.z + b1b.z, 0.f);
      a8[7] = fmaxf(rx*w0b.w + ry*w1b.w + rz*w2b.w + b1b.w, 0.f);
    } else {
      const int kc = k0 + sk;
      const float4 d0 = *(const float4*)(arow + kc);
      const float4 d1 = *(const float4*)(arow + kc + 4);
      const float4 a0 = *(const float4*)(adrow + kc);
      const float4 a1 = *(const float4*)(adrow + kc + 4);
      const float4 s0 = *(const float4*)(asrow + kc);
      const float4 s1 = *(const float4*)(asrow + kc + 4);
      a8[0] = a0.x - s0.x + d0.x; a8[1] = a0.y - s0.y + d0.y;
      a8[2] = a0.z - s0.z + d0.z; a8[3] = a0.w - s0.w + d0.w;
      a8[4] = a1.x - s1.x + d1.x; a8[5] = a1.y - s1.y + d1.y;
      a8[6] = a1.z - s1.z + d1.z; a8[7] = a1.w - s1.w + d1.w;
    }
    const half8 bv = *(const half8*)(p.Wt + (long)(cb + sr) * 384 + k0 + sk);

    __syncthreads();
    half8 av;
    #pragma unroll
    for (int j = 0; j < 8; j++) av[j] = (_Float16)a8[j];
    *(half8*)&As[sr][sk] = av;
    *(half8*)&Bs[sr][sk] = bv;
    __syncthreads();

    const half8 fa0 = *(const half8*)&As[wm*32 + l16][quad*8];
    const half8 fa1 = *(const half8*)&As[wm*32 + 16 + l16][quad*8];
    const half8 fb0 = *(const half8*)&Bs[wn*32 + l16][quad*8];
    const half8 fb1 = *(const half8*)&Bs[wn*32 + 16 + l16][quad*8];
    acc[0][0] = __builtin_amdgcn_mfma_f32_16x16x32_f16(fa0, fb0, acc[0][0], 0, 0, 0);
    acc[0][1] = __builtin_amdgcn_mfma_f32_16x16x32_f16(fa0, fb1, acc[0][1], 0, 0, 0);
    acc[1][0] = __builtin_amdgcn_mfma_f32_16x16x32_f16(fa1, fb0, acc[1][0], 0, 0, 0);
    acc[1][1] = __builtin_amdgcn_mfma_f32_16x16x32_f16(fa1, fb1, acc[1][1], 0, 0, 0);
  }

  float bi0 = 0.f, bi1 = 0.f;
  if (BIAS) {
    bi0 = p.bias[cb + wn*32 + l16];
    bi1 = p.bias[cb + wn*32 + 16 + l16];
  }
  #pragma unroll
  for (int i = 0; i < 2; i++) {
    const int base = rb + wm*32 + i*16;
    if (base < p.R) {
      const int r0 = base + quad*4;
      #pragma unroll
      for (int j = 0; j < 2; j++) {
        const int col = cb + wn*32 + j*16 + l16;
        const float bb = j ? bi1 : bi0;
        #pragma unroll
        for (int reg = 0; reg < 4; reg++) {
          float v = acc[i][j][reg] + bb;
          if (RELU) v = fmaxf(v, 0.f);
          C[(long)(r0 + reg) * 384 + col] = v;
        }
      }
    }
  }
}

template<int AMODE, bool GATHER, bool BIAS, bool RELU>
__global__ __launch_bounds__(256) void mgemm_kernel(GemmP p)
{
  __shared__ _Float16 As[64][40];
  __shared__ _Float16 Bs[64][40];
  mgemm_body<AMODE, GATHER, BIAS, RELU>(p, blockIdx.x, blockIdx.y, blockIdx.z,
                                        threadIdx.x, As, Bs);
}

// ---------------- fat1: fps0 || v0 || a_src0 -------------------------------
__global__ __launch_bounds__(256) void fat1_kernel(
    const float* fpos, int* fidx, float* fpout, GemmP gv, GemmP ga)
{
  __shared__ char buf[49664] __attribute__((aligned(16)));
  int bid = blockIdx.x; const int t = threadIdx.x;
  if (bid < 4) {
    float* spx = (float*)buf;
    float* spy = spx + 4096;
    float* spz = spy + 4096;
    unsigned long long* s_key = (unsigned long long*)(spz + 4096);
    fps_body<4096, 256>(fpos, fidx, fpout, bid, t, spx, spy, spz, s_key);
    return;
  }
  bid -= 4;
  H40 As = (H40)buf;
  H40 Bs = (H40)(buf + 64 * 40 * sizeof(_Float16));
  if (bid < 1536) {
    mgemm_body<0, false, true, false>(gv, bid & 63, (bid >> 6) % 6, bid / 384, t, As, Bs);
    return;
  }
  bid -= 1536;
  mgemm_body<0, false, false, false>(ga, bid & 63, (bid >> 6) % 6, bid / 384, t, As, Bs);
}

// ---------------- masked softmax over K + weighted sum + LayerNorm ---------
__global__ __launch_bounds__(128) void attnln_kernel(
    const float* __restrict__ alpha, const float* __restrict__ delta,
    const float* __restrict__ vbuf, const int* __restrict__ nbr,
    const float* __restrict__ vldb, const float* __restrict__ lng,
    const float* __restrict__ lnb, float* __restrict__ xout,
    int q0, long sCh, long sV, long sNb, long sX)
{
  const int ml = blockIdx.x, b = blockIdx.y;
  const int m = q0 + ml;
  alpha += (long)b * sCh; delta += (long)b * sCh; vbuf += (long)b * sV;
  nbr += (long)b * sNb; vldb += (long)b * sNb; xout += (long)b * sX;
  const int t = threadIdx.x;

  int nb[16]; float vl[16];
  #pragma unroll
  for (int k = 0; k < 16; k++) { nb[k] = nbr[m*16+k]; vl[k] = vldb[m*16+k]; }

  const long rbase = (long)ml * 16 * 384;
  float av[16][3];
  #pragma unroll
  for (int k = 0; k < 16; k++)
    #pragma unroll
    for (int i = 0; i < 3; i++) {
      const float a = alpha[rbase + k*384 + t + i*128];
      av[k][i] = (vl[k] > 0.5f) ? a : -1e30f;
    }
  float mx[3] = {-3.4e38f, -3.4e38f, -3.4e38f};
  #pragma unroll
  for (int k = 0; k < 16; k++)
    #pragma unroll
    for (int i = 0; i < 3; i++) mx[i] = fmaxf(mx[i], av[k][i]);
  float sm[3] = {0.f, 0.f, 0.f};
  #pragma unroll
  for (int k = 0; k < 16; k++)
    #pragma unroll
    for (int i = 0; i < 3; i++) { const float e = expf(av[k][i] - mx[i]); av[k][i] = e; sm[i] += e; }
  float rs[3];
  #pragma unroll
  for (int i = 0; i < 3; i++) rs[i] = 1.0f / sm[i];
  float o[3] = {0.f, 0.f, 0.f};
  #pragma unroll
  for (int k = 0; k < 16; k++) {
    const long nrow = (long)nb[k] * 384;
    #pragma unroll
    for (int i = 0; i < 3; i++) {
      const int dd = t + i * 128;
      const float vv = vbuf[nrow + dd] + delta[rbase + k*384 + dd];
      o[i] += (av[k][i] * rs[i] * vl[k]) * vv;
    }
  }
  __shared__ float sred[2];
  float s1 = o[0] + o[1] + o[2];
  #pragma unroll
  for (int off = 32; off; off >>= 1) s1 += __shfl_xor(s1, off);
  if ((t & 63) == 0) sred[t >> 6] = s1;
  __syncthreads();
  const float mean = (sred[0] + sred[1]) * (1.0f / 384.0f);
  __syncthreads();
  float s2 = 0.f;
  #pragma unroll
  for (int i = 0; i < 3; i++) { const float dd = o[i] - mean; s2 += dd * dd; }
  #pragma unroll
  for (int off = 32; off; off >>= 1) s2 += __shfl_xor(s2, off);
  if ((t & 63) == 0) sred[t >> 6] = s2;
  __syncthreads();
  const float var = (sred[0] + sred[1]) * (1.0f / 384.0f);
  const float rstd = 1.0f / sqrtf(var + 1e-5f);
  #pragma unroll
  for (int i = 0; i < 3; i++) {
    const int dd = t + i * 128;
    xout[(long)m * 384 + dd] = (o[i] - mean) * rstd * lng[dd] + lnb[dd];
  }
}

// ---------------- final projection + LayerNorm -----------------------------
__global__ __launch_bounds__(384) void feat_kernel(
    const float* __restrict__ x4, const float* __restrict__ pw,
    const float* __restrict__ pb, const float* __restrict__ g,
    const float* __restrict__ be, float* __restrict__ outf)
{
  const int row = blockIdx.x, b = blockIdx.y;
  const long r = (long)b * 16 + row;
  const int d = threadIdx.x;
  __shared__ float xs[384];
  xs[d] = x4[r * 384 + d];
  __syncthreads();
  float acc = pb[d];
  #pragma unroll 8
  for (int j = 0; j < 384; j++) acc = fmaf(xs[j], pw[(long)j * 384 + d], acc);
  __shared__ float sred[6];
  float s = acc;
  #pragma unroll
  for (int off = 32; off; off >>= 1) s += __shfl_xor(s, off);
  if ((d & 63) == 0) sred[d >> 6] = s;
  __syncthreads();
  const float mean = (sred[0]+sred[1]+sred[2]+sred[3]+sred[4]+sred[5]) * (1.0f/384.0f);
  __syncthreads();
  float dv = (acc - mean) * (acc - mean);
  #pragma unroll
  for (int off = 32; off; off >>= 1) dv += __shfl_xor(dv, off);
  if ((d & 63) == 0) sred[d >> 6] = dv;
  __syncthreads();
  const float var = (sred[0]+sred[1]+sred[2]+sred[3]+sred[4]+sred[5]) * (1.0f/384.0f);
  const float rstd = 1.0f / sqrtf(var + 1e-5f);
  outf[r * 384 + d] = (acc - mean) * rstd * g[d] + be[d];
}

// ---------------- pos + pad outputs ----------------------------------------
__global__ void tail_kernel(const float* __restrict__ p4, float* __restrict__ out)
{
  const int t = threadIdx.x;
  if (t < 192) out[t] = p4[t];
  if (t < 64) out[192 + 24576 + t] = 0.0f;
}

// ---------------------------------------------------------------------------
extern "C" void kernel_launch(void* const* d_in, const int* in_sizes, int n_in,
                              void* d_out, int out_size, void* d_ws, size_t ws_size,
                              hipStream_t stream)
{
  (void)in_sizes; (void)n_in; (void)out_size; (void)ws_size;
  const float* pts    = (const float*)d_in[0];
  const float* lin_w  = (const float*)d_in[1];
  const float* lin_b  = (const float*)d_in[2];
  const float* src_w  = (const float*)d_in[3];
  const float* dst_w  = (const float*)d_in[4];
  const float* pos_w1 = (const float*)d_in[5];
  const float* pos_b1 = (const float*)d_in[6];
  const float* pos_w2 = (const float*)d_in[7];
  const float* pos_b2 = (const float*)d_in[8];
  const float* attn_w = (const float*)d_in[9];
  const float* attn_b = (const float*)d_in[10];
  const float* ln_g   = (const float*)d_in[11];
  const float* ln_b   = (const float*)d_in[12];
  const float* proj_w = (const float*)d_in[13];
  const float* proj_b = (const float*)d_in[14];
  const float* pln_g  = (const float*)d_in[15];
  const float* pln_b  = (const float*)d_in[16];
  float* out = (float*)d_out;

  // ---- workspace layout (R5-proven, chunked) ----
  constexpr long SX0 = 4096L*384, SX1 = 1024L*384, SX2 = 256L*384, SX3 = 64L*384, SX4 = 16L*384;
  constexpr long SP0 = 4096L*3, SP1 = 1024L*3, SP2 = 256L*3, SP3 = 64L*3, SP4 = 16L*3;
  constexpr long SV  = 4096L*384;
  constexpr long SAD = 1024L*384;
  constexpr long SCH = 4096L*384;
  constexpr long SNB = 1024L*16;

  _Float16* wt = (_Float16*)d_ws;
  float* ws = (float*)(wt + 20L * 147456);
  float* x0 = ws; ws += 4*SX0;
  float* x1 = ws; ws += 4*SX1;
  float* x2 = ws; ws += 4*SX2;
  float* x3 = ws; ws += 4*SX3;
  float* x4 = ws; ws += 4*SX4;
  float* p0 = ws; ws += 4*SP0;
  float* p1 = ws; ws += 4*SP1;
  float* p2 = ws; ws += 4*SP2;
  float* p3 = ws; ws += 4*SP3;
  float* p4 = ws; ws += 4*SP4;
  float* vb = ws; ws += 4*SV;
  float* asb = ws; ws += 4*SV;
  float* adb = ws; ws += 4*SAD;
  float* db = ws; ws += 4*SCH;
  float* ab = ws; ws += 4*SCH;
  float* vld = ws; ws += 4*SNB;
  int* nb = (int*)ws; ws += 4*SNB;
  int* ix[4];
  ix[0] = (int*)ws; ws += 4*1024;
  ix[1] = (int*)ws; ws += 4*256;
  ix[2] = (int*)ws; ws += 4*64;
  ix[3] = (int*)ws; ws += 4*16;

  const int Ns[4] = {4096, 1024, 256, 64};
  const int Ms[4] = {1024, 256, 64, 16};
  const float R2[4] = {1.0f, 4.0f, 16.0f, 64.0f};
  float* X[5] = {x0, x1, x2, x3, x4};
  float* P[5] = {p0, p1, p2, p3, p4};
  long SPs[5] = {SP0, SP1, SP2, SP3, SP4};
  long SXs[5] = {SX0, SX1, SX2, SX3, SX4};

  split_kernel<<<dim3(4096, 4), 128, 0, stream>>>(pts, p0, x0);

  {
    TP tp{};
    tp.src[0] = lin_w; tp.src[1] = src_w; tp.src[2] = dst_w;
    tp.src[3] = pos_w2; tp.src[4] = attn_w;
    tp.dst = wt;
    transpose_kernel<<<dim3(12, 12, 20), 256, 0, stream>>>(tp);
  }

  // fat1: fps0 || v0 || a_src0  (all inputs from split/transpose only)
  {
    GemmP gv{}; gv.A = x0; gv.sA = SX0; gv.Wt = wt + (long)(0*4+0)*147456;
    gv.bias = lin_b; gv.C = vb; gv.sC = SV; gv.R = 4096;
    GemmP ga{}; ga.A = x0; ga.sA = SX0; ga.Wt = wt + (long)(1*4+0)*147456;
    ga.C = asb; ga.sC = SV; ga.R = 4096;
    fat1_kernel<<<dim3(4 + 1536 + 1536), 256, 0, stream>>>(p0, ix[0], p1, gv, ga);
  }

  // rest of FPS chain (standalone)
  fps_kernel<1024, 256><<<dim3(4), 256, 0, stream>>>(P[1], ix[1], P[2]);
  fps_kernel<256, 64><<<dim3(4), 64, 0, stream>>>(P[2], ix[2], P[3]);
  fps_kernel<64, 64><<<dim3(4), 64, 0, stream>>>(P[3], ix[3], P[4]);

  for (int s = 0; s < 4; s++) {
    const int N = Ns[s], M = Ms[s];
    switch (s) {
      case 0: knn_kernel<64><<<dim3(M, 4), 64, 0, stream>>>(P[s], P[s+1], N, M, nb, vld, R2[s]); break;
      case 1: knn_kernel<16><<<dim3(M, 4), 64, 0, stream>>>(P[s], P[s+1], N, M, nb, vld, R2[s]); break;
      case 2: knn_kernel<4><<<dim3(M, 4), 64, 0, stream>>>(P[s], P[s+1], N, M, nb, vld, R2[s]); break;
      default: knn_kernel<1><<<dim3(M, 4), 64, 0, stream>>>(P[s], P[s+1], N, M, nb, vld, R2[s]); break;
    }
    if (s > 0) {
      // v = x@lw + lb
      GemmP g{}; g.A = X[s]; g.sA = SXs[s]; g.Wt = wt + (long)(0*4+s)*147456; g.bias = lin_b + (long)s*384;
      g.C = vb; g.sC = SV; g.R = N;
      mgemm_kernel<0, false, true, false><<<dim3(N/64, 6, 4), 256, 0, stream>>>(g);
      // a_src = x@sw
      GemmP g2{}; g2.A = X[s]; g2.sA = SXs[s]; g2.Wt = wt + (long)(1*4+s)*147456;
      g2.C = asb; g2.sC = SV; g2.R = N;
      mgemm_kernel<0, false, false, false><<<dim3(N/64, 6, 4), 256, 0, stream>>>(g2);
    }
    // a_dst = x[idx]@dw
    {
      GemmP g{}; g.A = X[s]; g.sA = SXs[s]; g.Wt = wt + (long)(2*4+s)*147456;
      g.C = adb; g.sC = SAD; g.R = M; g.gather = ix[s]; g.sG = M;
      mgemm_kernel<0, true, false, false><<<dim3((M+63)/64, 6, 4), 256, 0, stream>>>(g);
    }
    const int nch = (M + 255) / 256;
    for (int c = 0; c < nch; c++) {
      const int q0 = c * 256;
      const int Mc = (M - q0 < 256) ? (M - q0) : 256;
      const int rows = Mc * 16;
      {
        GemmP g{}; g.Wt = wt + (long)(3*4+s)*147456; g.bias = pos_b2 + (long)s*384;
        g.C = db; g.sC = SCH; g.R = rows;
        g.qpos = P[s+1]; g.sQ = SPs[s+1]; g.pos = P[s]; g.sP = SPs[s];
        g.nbr = nb; g.sN = SNB; g.pw1 = pos_w1 + (long)s*1152; g.pb1 = pos_b1 + (long)s*384;
        g.row0 = q0 * 16;
        mgemm_kernel<1, false, true, true><<<dim3(rows/64, 6, 4), 256, 0, stream>>>(g);
      }
      {
        GemmP g{}; g.A = db; g.sA = SCH; g.Wt = wt + (long)(4*4+s)*147456; g.bias = attn_b + (long)s*384;
        g.C = ab; g.sC = SCH; g.R = rows;
        g.nbr = nb; g.sN = SNB; g.adst = adb; g.sAD = SAD; g.asrc = asb; g.sAS = SV;
        g.row0 = q0 * 16;
        mgemm_kernel<2, false, true, true><<<dim3(rows/64, 6, 4), 256, 0, stream>>>(g);
      }
      attnln_kernel<<<dim3(Mc, 4), 128, 0, stream>>>(
          ab, db, vb, nb, vld, ln_g + (long)s*384, ln_b + (long)s*384,
          X[s+1], q0, SCH, SV, SNB, (long)M*384);
    }
  }

  feat_kernel<<<dim3(16, 4), 384, 0, stream>>>(x4, proj_w, proj_b, pln_g, pln_b, out + 192);
  tail_kernel<<<1, 256, 0, stream>>>(p4, out);
}

// Round 10
// 1331.151 us; speedup vs baseline: 1.2549x; 1.0955x over previous
//
#include <hip/hip_runtime.h>
#include <math.h>

// ---------------------------------------------------------------------------
// GlobalSceneEncoder: 4-stage point-transformer encoder.
// FPS/KNN: bit-exact f32 replication of the numpy reference (no FMA,
// fixed summation order), u32/u64 monotone-key reductions.
// FPS v6: fused update+tournament (12 ops/pt), DPP wave-max, LDS pos cache.
// GEMMs: f16 MFMA w/ fp32 accum.
// Overlap: fat1 = fps0||v0||a_src0, fat2 = fps1||knn0||a_dst0,
//          sfat(s) = v||a_src||knn||a_dst for s=1..3.
// B=4, N0=4096, D=384, K=16.
// ---------------------------------------------------------------------------

using half8 = __attribute__((ext_vector_type(8))) _Float16;
using f32x4 = __attribute__((ext_vector_type(4))) float;

__device__ __forceinline__ void fps_prio()
{
#if __has_builtin(__builtin_amdgcn_s_setprio)
  __builtin_amdgcn_s_setprio(3);
#endif
}

__device__ __forceinline__ float d2f(float ax, float ay, float az,
                                     float bx, float by, float bz)
{
  // exact np order: ((dx*dx + dy*dy) + dz*dz), no contraction
  const float dx = __fsub_rn(ax, bx);
  const float dy = __fsub_rn(ay, by);
  const float dz = __fsub_rn(az, bz);
  return __fadd_rn(__fadd_rn(__fmul_rn(dx, dx), __fmul_rn(dy, dy)),
                   __fmul_rn(dz, dz));
}

// ---- DPP u32 max reduce across wave64, result broadcast via readlane ------
template<int CTRL>
__device__ __forceinline__ unsigned dppmax_step(unsigned v)
{
  const unsigned o = (unsigned)__builtin_amdgcn_update_dpp(
      (int)v, (int)v, CTRL, 0xF, 0xF, false);
  return o > v ? o : v;
}
__device__ __forceinline__ unsigned wave_max_bcast(unsigned v)
{
  v = dppmax_step<0x111>(v);   // row_shr:1
  v = dppmax_step<0x112>(v);   // row_shr:2
  v = dppmax_step<0x114>(v);   // row_shr:4
  v = dppmax_step<0x118>(v);   // row_shr:8
  v = dppmax_step<0x142>(v);   // row_bcast:15
  v = dppmax_step<0x143>(v);   // row_bcast:31
  return (unsigned)__builtin_amdgcn_readlane((int)v, 63);
}

// ---------------- split pts -> pos0, x0 ----------------
__global__ __launch_bounds__(128) void split_kernel(
    const float* __restrict__ pts, float* __restrict__ pos0, float* __restrict__ x0)
{
  const int n = blockIdx.x;
  const int b = blockIdx.y;
  const float* src = pts + ((long)b * 4096 + n) * 387;
  float* pd = pos0 + ((long)b * 4096 + n) * 3;
  float* xd = x0 + ((long)b * 4096 + n) * 384;
  for (int e = threadIdx.x; e < 387; e += 128) {
    float v = src[e];
    if (e < 3) pd[e] = v; else xd[e - 3] = v;
  }
}

// ---------------- weight transpose + f16 convert: Wt[n][k] = W[k][n] -------
struct TP { const float* src[5]; _Float16* dst; };
__global__ __launch_bounds__(256) void transpose_kernel(TP p)
{
  const int z = blockIdx.z;
  const float* S = p.src[z >> 2] + (long)(z & 3) * 147456;
  _Float16* Dst = p.dst + (long)z * 147456;
  const int k0 = blockIdx.x * 32, n0 = blockIdx.y * 32;
  __shared__ float tile[32][33];
  const int ti = threadIdx.x & 31, tj = threadIdx.x >> 5;
  #pragma unroll
  for (int p8 = 0; p8 < 32; p8 += 8)
    tile[tj + p8][ti] = S[(long)(k0 + tj + p8) * 384 + n0 + ti];
  __syncthreads();
  #pragma unroll
  for (int p8 = 0; p8 < 32; p8 += 8)
    Dst[(long)(n0 + tj + p8) * 384 + k0 + ti] = (_Float16)tile[ti][tj + p8];
}

// ---------------- FPS v6 body: fused update+tournament, DPP reduce ---------
// Contiguous ownership: thread t owns points [t*NPT, (t+1)*NPT) so
// lowest-lane tie-break == lowest-index tie-break.
template<int NPTS, int NTHR>
__device__ __forceinline__ void fps_body(
    const float* __restrict__ pos,
    int* __restrict__ idx_out, float* __restrict__ pos_out,
    int b, int t,
    float* __restrict__ spx, float* __restrict__ spy, float* __restrict__ spz,
    unsigned long long* __restrict__ s_key)
{
  constexpr int NPT = NPTS / NTHR;
  constexpr int NW = NTHR / 64;
  constexpr int M = NPTS / 4;
  pos += (long)b * NPTS * 3; idx_out += (long)b * M; pos_out += (long)b * M * 3;

  float px[NPT], py[NPT], pz[NPT], dmin[NPT];
  #pragma unroll
  for (int i = 0; i < NPT; i++) {
    const int j = t * NPT + i;
    px[i] = pos[j*3]; py[i] = pos[j*3+1]; pz[i] = pos[j*3+2];
    spx[j] = px[i]; spy[j] = py[i]; spz[j] = pz[i];
  }
  const float sx = pos[0], sy = pos[1], sz = pos[2];
  float bv = 0.f; int bi = 0;
  #pragma unroll
  for (int i = 0; i < NPT; i++) {
    const float dd = d2f(px[i], py[i], pz[i], sx, sy, sz);
    dmin[i] = dd;
    if (i == 0) { bv = dd; bi = 0; }
    else { const bool g = dd > bv; bv = g ? dd : bv; bi = g ? i : bi; }
  }
  if (t == 0) { idx_out[0] = 0; pos_out[0] = sx; pos_out[1] = sy; pos_out[2] = sz; }
  if (NW > 1) __syncthreads();   // spx/spy/spz visible

  for (int m = 1; m < M; ++m) {
    const unsigned myub = __float_as_uint(bv);
    const unsigned wmax = wave_max_bcast(myub);
    const unsigned long long mk = __ballot(myub == wmax);
    const int srclane = __builtin_ctzll(mk);
    const int lbi = __shfl(bi, srclane);
    const int wj = ((t & ~63) + srclane) * NPT + lbi;   // wave winner, global

    int sel;
    if (NW > 1) {
      const int p = m & 1;
      if ((t & 63) == 0)
        s_key[p*NW + (t >> 6)] =
            ((unsigned long long)wmax << 32) | (unsigned)(NPTS - 1 - wj);
      __syncthreads();
      unsigned long long kb = s_key[p*NW];
      #pragma unroll
      for (int w2 = 1; w2 < NW; w2++) {
        const unsigned long long o = s_key[p*NW + w2];
        if (o > kb) kb = o;
      }
      sel = NPTS - 1 - (int)(kb & 0xFFFFFFFFu);
    } else {
      sel = wj;
    }
    const float qx = spx[sel], qy = spy[sel], qz = spz[sel];
    if (t == 0) { idx_out[m] = sel; pos_out[m*3] = qx; pos_out[m*3+1] = qy; pos_out[m*3+2] = qz; }
    float nbv = 0.f; int nbi = 0;
    #pragma unroll
    for (int i = 0; i < NPT; i++) {
      const float dd = d2f(px[i], py[i], pz[i], qx, qy, qz);
      const float nd = fminf(dmin[i], dd);
      dmin[i] = nd;
      if (i == 0) { nbv = nd; nbi = 0; }
      else { const bool g = nd > nbv; nbv = g ? nd : nbv; nbi = g ? i : nbi; }
    }
    bv = nbv; bi = nbi;
  }
}

template<int NPTS, int NTHR>
__global__ __launch_bounds__(NTHR, 1) void fps_kernel(
    const float* __restrict__ pos,
    int* __restrict__ idx_out, float* __restrict__ pos_out)
{
  __shared__ float spx[NPTS], spy[NPTS], spz[NPTS];
  __shared__ unsigned long long s_key[2 * (NTHR > 64 ? NTHR / 64 : 1)];
  fps_body<NPTS, NTHR>(pos, idx_out, pos_out, blockIdx.x, threadIdx.x,
                       spx, spy, spz, s_key);
}

// ---------------- KNN body: one wave/query, 16 passes, u64 (dist,j) keys ---
template<int C>
__device__ __forceinline__ void knn_body(
    const float* __restrict__ pos, const float* __restrict__ qpos, int M,
    int* __restrict__ nbr, float* __restrict__ vld, float r2,
    int b, int m, int lane)
{
  pos += (long)b * (C * 64) * 3; qpos += (long)b * M * 3;
  nbr += (long)b * (1024 * 16); vld += (long)b * (1024 * 16);
  const float qx = qpos[m*3], qy = qpos[m*3+1], qz = qpos[m*3+2];
  unsigned long long key[C];
  #pragma unroll
  for (int c = 0; c < C; c++) {
    const int j = c * 64 + lane;
    const float dd = d2f(pos[j*3], pos[j*3+1], pos[j*3+2], qx, qy, qz);
    key[c] = ((unsigned long long)__float_as_uint(dd) << 32) | (unsigned)j;
  }
  unsigned long long prev = 0;
  for (int k = 0; k < 16; k++) {
    unsigned long long best = ~0ull;
    #pragma unroll
    for (int c = 0; c < C; c++) {
      const bool take = (k == 0) || (key[c] > prev);
      if (take && key[c] < best) best = key[c];
    }
    #pragma unroll
    for (int off = 32; off; off >>= 1) {
      const unsigned long long o = __shfl_xor(best, off);
      if (o < best) best = o;
    }
    prev = best;
    if (lane == 0) {
      nbr[m*16+k] = (int)(best & 0xFFFFFFFFu);
      const float dd = __uint_as_float((unsigned)(best >> 32));
      vld[m*16+k] = (dd <= r2) ? 1.0f : 0.0f;
    }
  }
}

template<int C>
__global__ __launch_bounds__(64) void knn_kernel(
    const float* __restrict__ pos, const float* __restrict__ qpos,
    int N, int M, int* __restrict__ nbr, float* __restrict__ vld, float r2)
{
  (void)N;
  knn_body<C>(pos, qpos, M, nbr, vld, r2, blockIdx.y, blockIdx.x, threadIdx.x);
}

// ---------------- f16 MFMA GEMM body, 64x64 tile, BK=32 --------------------
struct GemmP {
  const float* A; long sA;
  const _Float16* Wt;          // pre-transposed f16 weights: Wt[n][k]
  const float* bias;
  float* C; long sC;
  int R;
  const int* gather; long sG;
  const float* qpos; long sQ;
  const float* pos;  long sP;
  const int* nbr;    long sN;
  const float* pw1;
  const float* pb1;
  const float* adst; long sAD;
  const float* asrc; long sAS;
  int row0;
};

typedef _Float16 (*H40)[40];

template<int AMODE, bool GATHER, bool BIAS, bool RELU>
__device__ __forceinline__ void mgemm_body(
    const GemmP& p, int bx, int by, int bz, int t, H40 As, H40 Bs)
{
  const int b = bz;
  const int rb = bx * 64;
  const int cb = by * 64;
  const float* A = p.A ? (p.A + (long)b * p.sA) : nullptr;
  float* C = p.C + (long)b * p.sC;
  const int* gat = GATHER ? (p.gather + (long)b * p.sG) : nullptr;
  const int* nbrb = (AMODE != 0) ? (p.nbr + (long)b * p.sN) : nullptr;

  const int w = t >> 6, lane = t & 63;
  const int wm = w & 1, wn = w >> 1;
  const int quad = lane >> 4, l16 = lane & 15;

  f32x4 acc[2][2] = {};

  const int sr = t >> 2;
  const int sk = (t & 3) << 3;
  const int ar = rb + sr;

  const float* arow = nullptr;
  const float* adrow = nullptr;
  const float* asrow = nullptr;
  bool avalid = true;
  float rx = 0.f, ry = 0.f, rz = 0.f;
  if (AMODE == 0) {
    avalid = (ar < p.R);
    long srcrow = 0;
    if (avalid) srcrow = GATHER ? (long)gat[ar] : (long)ar;
    arow = A + srcrow * 384;
  } else {
    const int grow = p.row0 + ar;
    const int mq = grow >> 4;
    const int n = nbrb[grow];
    if (AMODE == 1) {
      const float* qposb = p.qpos + (long)b * p.sQ;
      const float* posb = p.pos + (long)b * p.sP;
      rx = qposb[mq*3+0] - posb[n*3+0];
      ry = qposb[mq*3+1] - posb[n*3+1];
      rz = qposb[mq*3+2] - posb[n*3+2];
    } else {
      arow = A + (long)ar * 384;
      adrow = p.adst + (long)b * p.sAD + (long)mq * 384;
      asrow = p.asrc + (long)b * p.sAS + (long)n * 384;
    }
  }

  for (int k0 = 0; k0 < 384; k0 += 32) {
    float a8[8];
    if (AMODE == 0) {
      if (avalid) {
        const float4 u = *(const float4*)(arow + k0 + sk);
        const float4 v = *(const float4*)(arow + k0 + sk + 4);
        a8[0]=u.x; a8[1]=u.y; a8[2]=u.z; a8[3]=u.w;
        a8[4]=v.x; a8[5]=v.y; a8[6]=v.z; a8[7]=v.w;
      } else {
        #pragma unroll
        for (int j = 0; j < 8; j++) a8[j] = 0.f;
      }
    } else if (AMODE == 1) {
      const int kc = k0 + sk;
      const float4 w0a = *(const float4*)(p.pw1 + kc);
      const float4 w0b = *(const float4*)(p.pw1 + kc + 4);
      const float4 w1a = *(const float4*)(p.pw1 + 384 + kc);
      const float4 w1b = *(const float4*)(p.pw1 + 384 + kc + 4);
      const float4 w2a = *(const float4*)(p.pw1 + 768 + kc);
      const float4 w2b = *(const float4*)(p.pw1 + 768 + kc + 4);
      const float4 b1a = *(const float4*)(p.pb1 + kc);
      const float4 b1b = *(const float4*)(p.pb1 + kc + 4);
      a8[0] = fmaxf(rx*w0a.x + ry*w1a.x + rz*w2a.x + b1a.x, 0.f);
      a8[1] = fmaxf(rx*w0a.y + ry*w1a.y + rz*w2a.y + b1a.y, 0.f);
      a8[2] = fmaxf(rx*w0a.z + ry*w1a.z + rz*w2a.z + b1a.z, 0.f);
      a8[3] = fmaxf(rx*w0a.w + ry*w1a.w + rz*w2a.w + b1a.w, 0.f);
      a8[4] = fmaxf(rx*w0b.x + ry*w1b.x + rz*w2b.x + b1b.x, 0.f);
      a8[5] = fmaxf(rx*w0b.y + ry*w1b.y + rz*w2b.y + b1b.y, 0.f);
      a8[6] = fmaxf(rx*w0b.z + ry*w1b.z + rz*w2b.z + b1b.z, 0.f);
      a8[7] = fmaxf(rx*w0b.w + ry*w1b.w + rz*w2b.w + b1b.w, 0.f);
    } else {
      const int kc = k0 + sk;
      const float4 d0 = *(const float4*)(arow + kc);
      const float4 d1 = *(const float4*)(arow + kc + 4);
      const float4 a0 = *(const float4*)(adrow + kc);
      const float4 a1 = *(const float4*)(adrow + kc + 4);
      const float4 s0 = *(const float4*)(asrow + kc);
      const float4 s1 = *(const float4*)(asrow + kc + 4);
      a8[0] = a0.x - s0.x + d0.x; a8[1] = a0.y - s0.y + d0.y;
      a8[2] = a0.z - s0.z + d0.z; a8[3] = a0.w - s0.w + d0.w;
      a8[4] = a1.x - s1.x + d1.x; a8[5] = a1.y - s1.y + d1.y;
      a8[6] = a1.z - s1.z + d1.z; a8[7] = a1.w - s1.w + d1.w;
    }
    const half8 bv = *(const half8*)(p.Wt + (long)(cb + sr) * 384 + k0 + sk);

    __syncthreads();
    half8 av;
    #pragma unroll
    for (int j = 0; j < 8; j++) av[j] = (_Float16)a8[j];
    *(half8*)&As[sr][sk] = av;
    *(half8*)&Bs[sr][sk] = bv;
    __syncthreads();

    const half8 fa0 = *(const half8*)&As[wm*32 + l16][quad*8];
    const half8 fa1 = *(const half8*)&As[wm*32 + 16 + l16][quad*8];
    const half8 fb0 = *(const half8*)&Bs[wn*32 + l16][quad*8];
    const half8 fb1 = *(const half8*)&Bs[wn*32 + 16 + l16][quad*8];
    acc[0][0] = __builtin_amdgcn_mfma_f32_16x16x32_f16(fa0, fb0, acc[0][0], 0, 0, 0);
    acc[0][1] = __builtin_amdgcn_mfma_f32_16x16x32_f16(fa0, fb1, acc[0][1], 0, 0, 0);
    acc[1][0] = __builtin_amdgcn_mfma_f32_16x16x32_f16(fa1, fb0, acc[1][0], 0, 0, 0);
    acc[1][1] = __builtin_amdgcn_mfma_f32_16x16x32_f16(fa1, fb1, acc[1][1], 0, 0, 0);
  }

  float bi0 = 0.f, bi1 = 0.f;
  if (BIAS) {
    bi0 = p.bias[cb + wn*32 + l16];
    bi1 = p.bias[cb + wn*32 + 16 + l16];
  }
  #pragma unroll
  for (int i = 0; i < 2; i++) {
    const int base = rb + wm*32 + i*16;
    if (base < p.R) {
      const int r0 = base + quad*4;
      #pragma unroll
      for (int j = 0; j < 2; j++) {
        const int col = cb + wn*32 + j*16 + l16;
        const float bb = j ? bi1 : bi0;
        #pragma unroll
        for (int reg = 0; reg < 4; reg++) {
          float v = acc[i][j][reg] + bb;
          if (RELU) v = fmaxf(v, 0.f);
          C[(long)(r0 + reg) * 384 + col] = v;
        }
      }
    }
  }
}

template<int AMODE, bool GATHER, bool BIAS, bool RELU>
__global__ __launch_bounds__(256) void mgemm_kernel(GemmP p)
{
  __shared__ _Float16 As[64][40];
  __shared__ _Float16 Bs[64][40];
  mgemm_body<AMODE, GATHER, BIAS, RELU>(p, blockIdx.x, blockIdx.y, blockIdx.z,
                                        threadIdx.x, As, Bs);
}

// ---------------- fat1: fps0 || v0 || a_src0 -------------------------------
__global__ __launch_bounds__(256) void fat1_kernel(
    const float* fpos, int* fidx, float* fpout, GemmP gv, GemmP ga)
{
  __shared__ char buf[49664] __attribute__((aligned(16)));
  int bid = blockIdx.x; const int t = threadIdx.x;
  if (bid < 4) {
    fps_prio();
    float* spx = (float*)buf;
    float* spy = spx + 4096;
    float* spz = spy + 4096;
    unsigned long long* s_key = (unsigned long long*)(spz + 4096);
    fps_body<4096, 256>(fpos, fidx, fpout, bid, t, spx, spy, spz, s_key);
    return;
  }
  bid -= 4;
  H40 As = (H40)buf;
  H40 Bs = (H40)(buf + 64 * 40 * sizeof(_Float16));
  if (bid < 1536) {
    mgemm_body<0, false, true, false>(gv, bid & 63, (bid >> 6) % 6, bid / 384, t, As, Bs);
    return;
  }
  bid -= 1536;
  mgemm_body<0, false, false, false>(ga, bid & 63, (bid >> 6) % 6, bid / 384, t, As, Bs);
}

// ---------------- fat2: fps1 || knn0 || a_dst0 -----------------------------
__global__ __launch_bounds__(256) void fat2_kernel(
    const float* fpos, int* fidx, float* fpout,
    const float* kpos, const float* kqpos, int* knbr, float* kvld, float kr2,
    GemmP gd)
{
  __shared__ char buf[12352] __attribute__((aligned(16)));
  int bid = blockIdx.x; const int t = threadIdx.x;
  if (bid < 4) {
    fps_prio();
    float* spx = (float*)buf;
    float* spy = spx + 1024;
    float* spz = spy + 1024;
    unsigned long long* s_key = (unsigned long long*)(spz + 1024);
    fps_body<1024, 256>(fpos, fidx, fpout, bid, t, spx, spy, spz, s_key);
    return;
  }
  bid -= 4;
  if (bid < 1024) {
    const int b = bid >> 8;                 // 256 blocks per batch
    const int q = (bid & 255) * 4 + (t >> 6);
    knn_body<64>(kpos, kqpos, 1024, knbr, kvld, kr2, b, q, t & 63);
    return;
  }
  bid -= 1024;
  H40 As = (H40)buf;
  H40 Bs = (H40)(buf + 64 * 40 * sizeof(_Float16));
  // a_dst0: grid (16,6,4)
  mgemm_body<0, true, false, false>(gd, bid & 15, (bid >> 4) % 6, bid / 96, t, As, Bs);
}

// ---------------- sfat(s>=1): v || a_src || knn || a_dst -------------------
template<int C>
__global__ __launch_bounds__(256) void sfat_kernel(
    GemmP gv, GemmP ga, GemmP gd,
    const float* kpos, const float* kqpos, int kM,
    int* knbr, float* kvld, float kr2,
    int nv, int gxv, int nk, int gxd)
{
  __shared__ char buf[10240] __attribute__((aligned(16)));
  int bid = blockIdx.x; const int t = threadIdx.x;
  H40 As = (H40)buf;
  H40 Bs = (H40)(buf + 64 * 40 * sizeof(_Float16));
  if (bid < nv) {
    mgemm_body<0, false, true, false>(gv, bid % gxv, (bid / gxv) % 6, bid / (gxv * 6), t, As, Bs);
    return;
  }
  bid -= nv;
  if (bid < nv) {
    mgemm_body<0, false, false, false>(ga, bid % gxv, (bid / gxv) % 6, bid / (gxv * 6), t, As, Bs);
    return;
  }
  bid -= nv;
  if (bid < nk) {
    const int qpb = kM >> 2;                // blocks per batch
    const int b = bid / qpb;
    const int q = (bid % qpb) * 4 + (t >> 6);
    knn_body<C>(kpos, kqpos, kM, knbr, kvld, kr2, b, q, t & 63);
    return;
  }
  bid -= nk;
  mgemm_body<0, true, false, false>(gd, bid % gxd, (bid / gxd) % 6, bid / (gxd * 6), t, As, Bs);
}

// ---------------- masked softmax over K + weighted sum + LayerNorm ---------
__global__ __launch_bounds__(128) void attnln_kernel(
    const float* __restrict__ alpha, const float* __restrict__ delta,
    const float* __restrict__ vbuf, const int* __restrict__ nbr,
    const float* __restrict__ vldb, const float* __restrict__ lng,
    const float* __restrict__ lnb, float* __restrict__ xout,
    int q0, long sCh, long sV, long sNb, long sX)
{
  const int ml = blockIdx.x, b = blockIdx.y;
  const int m = q0 + ml;
  alpha += (long)b * sCh; delta += (long)b * sCh; vbuf += (long)b * sV;
  nbr += (long)b * sNb; vldb += (long)b * sNb; xout += (long)b * sX;
  const int t = threadIdx.x;

  int nb[16]; float vl[16];
  #pragma unroll
  for (int k = 0; k < 16; k++) { nb[k] = nbr[m*16+k]; vl[k] = vldb[m*16+k]; }

  const long rbase = (long)ml * 16 * 384;
  float av[16][3];
  #pragma unroll
  for (int k = 0; k < 16; k++)
    #pragma unroll
    for (int i = 0; i < 3; i++) {
      const float a = alpha[rbase + k*384 + t + i*128];
      av[k][i] = (vl[k] > 0.5f) ? a : -1e30f;
    }
  float mx[3] = {-3.4e38f, -3.4e38f, -3.4e38f};
  #pragma unroll
  for (int k = 0; k < 16; k++)
    #pragma unroll
    for (int i = 0; i < 3; i++) mx[i] = fmaxf(mx[i], av[k][i]);
  float sm[3] = {0.f, 0.f, 0.f};
  #pragma unroll
  for (int k = 0; k < 16; k++)
    #pragma unroll
    for (int i = 0; i < 3; i++) { const float e = expf(av[k][i] - mx[i]); av[k][i] = e; sm[i] += e; }
  float rs[3];
  #pragma unroll
  for (int i = 0; i < 3; i++) rs[i] = 1.0f / sm[i];
  float o[3] = {0.f, 0.f, 0.f};
  #pragma unroll
  for (int k = 0; k < 16; k++) {
    const long nrow = (long)nb[k] * 384;
    #pragma unroll
    for (int i = 0; i < 3; i++) {
      const int dd = t + i * 128;
      const float vv = vbuf[nrow + dd] + delta[rbase + k*384 + dd];
      o[i] += (av[k][i] * rs[i] * vl[k]) * vv;
    }
  }
  __shared__ float sred[2];
  float s1 = o[0] + o[1] + o[2];
  #pragma unroll
  for (int off = 32; off; off >>= 1) s1 += __shfl_xor(s1, off);
  if ((t & 63) == 0) sred[t >> 6] = s1;
  __syncthreads();
  const float mean = (sred[0] + sred[1]) * (1.0f / 384.0f);
  __syncthreads();
  float s2 = 0.f;
  #pragma unroll
  for (int i = 0; i < 3; i++) { const float dd = o[i] - mean; s2 += dd * dd; }
  #pragma unroll
  for (int off = 32; off; off >>= 1) s2 += __shfl_xor(s2, off);
  if ((t & 63) == 0) sred[t >> 6] = s2;
  __syncthreads();
  const float var = (sred[0] + sred[1]) * (1.0f / 384.0f);
  const float rstd = 1.0f / sqrtf(var + 1e-5f);
  #pragma unroll
  for (int i = 0; i < 3; i++) {
    const int dd = t + i * 128;
    xout[(long)m * 384 + dd] = (o[i] - mean) * rstd * lng[dd] + lnb[dd];
  }
}

// ---------------- final projection + LayerNorm -----------------------------
__global__ __launch_bounds__(384) void feat_kernel(
    const float* __restrict__ x4, const float* __restrict__ pw,
    const float* __restrict__ pb, const float* __restrict__ g,
    const float* __restrict__ be, float* __restrict__ outf)
{
  const int row = blockIdx.x, b = blockIdx.y;
  const long r = (long)b * 16 + row;
  const int d = threadIdx.x;
  __shared__ float xs[384];
  xs[d] = x4[r * 384 + d];
  __syncthreads();
  float acc = pb[d];
  #pragma unroll 8
  for (int j = 0; j < 384; j++) acc = fmaf(xs[j], pw[(long)j * 384 + d], acc);
  __shared__ float sred[6];
  float s = acc;
  #pragma unroll
  for (int off = 32; off; off >>= 1) s += __shfl_xor(s, off);
  if ((d & 63) == 0) sred[d >> 6] = s;
  __syncthreads();
  const float mean = (sred[0]+sred[1]+sred[2]+sred[3]+sred[4]+sred[5]) * (1.0f/384.0f);
  __syncthreads();
  float dv = (acc - mean) * (acc - mean);
  #pragma unroll
  for (int off = 32; off; off >>= 1) dv += __shfl_xor(dv, off);
  if ((d & 63) == 0) sred[d >> 6] = dv;
  __syncthreads();
  const float var = (sred[0]+sred[1]+sred[2]+sred[3]+sred[4]+sred[5]) * (1.0f/384.0f);
  const float rstd = 1.0f / sqrtf(var + 1e-5f);
  outf[r * 384 + d] = (acc - mean) * rstd * g[d] + be[d];
}

// ---------------- pos + pad outputs ----------------------------------------
__global__ void tail_kernel(const float* __restrict__ p4, float* __restrict__ out)
{
  const int t = threadIdx.x;
  if (t < 192) out[t] = p4[t];
  if (t < 64) out[192 + 24576 + t] = 0.0f;
}

// ---------------------------------------------------------------------------
extern "C" void kernel_launch(void* const* d_in, const int* in_sizes, int n_in,
                              void* d_out, int out_size, void* d_ws, size_t ws_size,
                              hipStream_t stream)
{
  (void)in_sizes; (void)n_in; (void)out_size; (void)ws_size;
  const float* pts    = (const float*)d_in[0];
  const float* lin_w  = (const float*)d_in[1];
  const float* lin_b  = (const float*)d_in[2];
  const float* src_w  = (const float*)d_in[3];
  const float* dst_w  = (const float*)d_in[4];
  const float* pos_w1 = (const float*)d_in[5];
  const float* pos_b1 = (const float*)d_in[6];
  const float* pos_w2 = (const float*)d_in[7];
  const float* pos_b2 = (const float*)d_in[8];
  const float* attn_w = (const float*)d_in[9];
  const float* attn_b = (const float*)d_in[10];
  const float* ln_g   = (const float*)d_in[11];
  const float* ln_b   = (const float*)d_in[12];
  const float* proj_w = (const float*)d_in[13];
  const float* proj_b = (const float*)d_in[14];
  const float* pln_g  = (const float*)d_in[15];
  const float* pln_b  = (const float*)d_in[16];
  float* out = (float*)d_out;

  // ---- workspace layout (R5-proven, chunked) ----
  constexpr long SX0 = 4096L*384, SX1 = 1024L*384, SX2 = 256L*384, SX3 = 64L*384, SX4 = 16L*384;
  constexpr long SP0 = 4096L*3, SP1 = 1024L*3, SP2 = 256L*3, SP3 = 64L*3, SP4 = 16L*3;
  constexpr long SV  = 4096L*384;
  constexpr long SAD = 1024L*384;
  constexpr long SCH = 4096L*384;
  constexpr long SNB = 1024L*16;

  _Float16* wt = (_Float16*)d_ws;
  float* ws = (float*)(wt + 20L * 147456);
  float* x0 = ws; ws += 4*SX0;
  float* x1 = ws; ws += 4*SX1;
  float* x2 = ws; ws += 4*SX2;
  float* x3 = ws; ws += 4*SX3;
  float* x4 = ws; ws += 4*SX4;
  float* p0 = ws; ws += 4*SP0;
  float* p1 = ws; ws += 4*SP1;
  float* p2 = ws; ws += 4*SP2;
  float* p3 = ws; ws += 4*SP3;
  float* p4 = ws; ws += 4*SP4;
  float* vb = ws; ws += 4*SV;
  float* asb = ws; ws += 4*SV;
  float* adb = ws; ws += 4*SAD;
  float* db = ws; ws += 4*SCH;
  float* ab = ws; ws += 4*SCH;
  float* vld = ws; ws += 4*SNB;
  int* nb = (int*)ws; ws += 4*SNB;
  int* ix[4];
  ix[0] = (int*)ws; ws += 4*1024;
  ix[1] = (int*)ws; ws += 4*256;
  ix[2] = (int*)ws; ws += 4*64;
  ix[3] = (int*)ws; ws += 4*16;

  const int Ns[4] = {4096, 1024, 256, 64};
  const int Ms[4] = {1024, 256, 64, 16};
  const float R2[4] = {1.0f, 4.0f, 16.0f, 64.0f};
  float* X[5] = {x0, x1, x2, x3, x4};
  float* P[5] = {p0, p1, p2, p3, p4};
  long SPs[5] = {SP0, SP1, SP2, SP3, SP4};
  long SXs[5] = {SX0, SX1, SX2, SX3, SX4};

  split_kernel<<<dim3(4096, 4), 128, 0, stream>>>(pts, p0, x0);

  {
    TP tp{};
    tp.src[0] = lin_w; tp.src[1] = src_w; tp.src[2] = dst_w;
    tp.src[3] = pos_w2; tp.src[4] = attn_w;
    tp.dst = wt;
    transpose_kernel<<<dim3(12, 12, 20), 256, 0, stream>>>(tp);
  }

  // fat1: fps0 || v0 || a_src0
  {
    GemmP gv{}; gv.A = x0; gv.sA = SX0; gv.Wt = wt + (long)(0*4+0)*147456;
    gv.bias = lin_b; gv.C = vb; gv.sC = SV; gv.R = 4096;
    GemmP ga{}; ga.A = x0; ga.sA = SX0; ga.Wt = wt + (long)(1*4+0)*147456;
    ga.C = asb; ga.sC = SV; ga.R = 4096;
    fat1_kernel<<<dim3(4 + 1536 + 1536), 256, 0, stream>>>(p0, ix[0], p1, gv, ga);
  }

  // fat2: fps1 || knn0 || a_dst0  (p1, ix[0] from fat1 — prior launch)
  {
    GemmP gd{}; gd.A = x0; gd.sA = SX0; gd.Wt = wt + (long)(2*4+0)*147456;
    gd.C = adb; gd.sC = SAD; gd.R = 1024; gd.gather = ix[0]; gd.sG = 1024;
    fat2_kernel<<<dim3(4 + 1024 + 384), 256, 0, stream>>>(
        p1, ix[1], p2, p0, p1, nb, vld, R2[0], gd);
  }

  // fps2, fps3 (standalone, tiny)
  fps_kernel<256, 64><<<dim3(4), 64, 0, stream>>>(P[2], ix[2], P[3]);
  fps_kernel<64, 64><<<dim3(4), 64, 0, stream>>>(P[3], ix[3], P[4]);

  // stage 0 tail: delta/alpha/attnln chunks (nb, adb from fat2; vb, asb from fat1)
  for (int c = 0; c < 4; c++) {
    const int q0 = c * 256;
    const int rows = 256 * 16;
    {
      GemmP g{}; g.Wt = wt + (long)(3*4+0)*147456; g.bias = pos_b2;
      g.C = db; g.sC = SCH; g.R = rows;
      g.qpos = p1; g.sQ = SP1; g.pos = p0; g.sP = SP0;
      g.nbr = nb; g.sN = SNB; g.pw1 = pos_w1; g.pb1 = pos_b1;
      g.row0 = q0 * 16;
      mgemm_kernel<1, false, true, true><<<dim3(rows/64, 6, 4), 256, 0, stream>>>(g);
    }
    {
      GemmP g{}; g.A = db; g.sA = SCH; g.Wt = wt + (long)(4*4+0)*147456; g.bias = attn_b;
      g.C = ab; g.sC = SCH; g.R = rows;
      g.nbr = nb; g.sN = SNB; g.adst = adb; g.sAD = SAD; g.asrc = asb; g.sAS = SV;
      g.row0 = q0 * 16;
      mgemm_kernel<2, false, true, true><<<dim3(rows/64, 6, 4), 256, 0, stream>>>(g);
    }
    attnln_kernel<<<dim3(256, 4), 128, 0, stream>>>(
        ab, db, vb, nb, vld, ln_g, ln_b, x1, q0, SCH, SV, SNB, 1024L*384);
  }

  // stages 1..3
  for (int s = 1; s < 4; s++) {
    const int N = Ns[s], M = Ms[s];
    const int gxv = N / 64, gxd = (M + 63) / 64;
    const int nv = gxv * 24, nk = M, nd = gxd * 24;
    {
      GemmP gv{}; gv.A = X[s]; gv.sA = SXs[s]; gv.Wt = wt + (long)(0*4+s)*147456;
      gv.bias = lin_b + (long)s*384; gv.C = vb; gv.sC = SV; gv.R = N;
      GemmP ga{}; ga.A = X[s]; ga.sA = SXs[s]; ga.Wt = wt + (long)(1*4+s)*147456;
      ga.C = asb; ga.sC = SV; ga.R = N;
      GemmP gd{}; gd.A = X[s]; gd.sA = SXs[s]; gd.Wt = wt + (long)(2*4+s)*147456;
      gd.C = adb; gd.sC = SAD; gd.R = M; gd.gather = ix[s]; gd.sG = M;
      const int total = nv + nv + nk + nd;
      switch (s) {
        case 1: sfat_kernel<16><<<dim3(total), 256, 0, stream>>>(
            gv, ga, gd, P[s], P[s+1], M, nb, vld, R2[s], nv, gxv, nk, gxd); break;
        case 2: sfat_kernel<4><<<dim3(total), 256, 0, stream>>>(
            gv, ga, gd, P[s], P[s+1], M, nb, vld, R2[s], nv, gxv, nk, gxd); break;
        default: sfat_kernel<1><<<dim3(total), 256, 0, stream>>>(
            gv, ga, gd, P[s], P[s+1], M, nb, vld, R2[s], nv, gxv, nk, gxd); break;
      }
    }
    const int rows = M * 16;
    const int gx = rows / 64;
    {
      GemmP g{}; g.Wt = wt + (long)(3*4+s)*147456; g.bias = pos_b2 + (long)s*384;
      g.C = db; g.sC = SCH; g.R = rows;
      g.qpos = P[s+1]; g.sQ = SPs[s+1]; g.pos = P[s]; g.sP = SPs[s];
      g.nbr = nb; g.sN = SNB; g.pw1 = pos_w1 + (long)s*1152; g.pb1 = pos_b1 + (long)s*384;
      g.row0 = 0;
      mgemm_kernel<1, false, true, true><<<dim3(gx, 6, 4), 256, 0, stream>>>(g);
    }
    {
      GemmP g{}; g.A = db; g.sA = SCH; g.Wt = wt + (long)(4*4+s)*147456;
      g.bias = attn_b + (long)s*384; g.C = ab; g.sC = SCH; g.R = rows;
      g.nbr = nb; g.sN = SNB; g.adst = adb; g.sAD = SAD; g.asrc = asb; g.sAS = SV;
      g.row0 = 0;
      mgemm_kernel<2, false, true, true><<<dim3(gx, 6, 4), 256, 0, stream>>>(g);
    }
    attnln_kernel<<<dim3(M, 4), 128, 0, stream>>>(
        ab, db, vb, nb, vld, ln_g + (long)s*384, ln_b + (long)s*384,
        X[s+1], 0, SCH, SV, SNB, (long)M*384);
  }

  feat_kernel<<<dim3(16, 4), 384, 0, stream>>>(x4, proj_w, proj_b, pln_g, pln_b, out + 192);
  tail_kernel<<<1, 256, 0, stream>>>(p4, out);
}